// Round 1
// baseline (554.218 us; speedup 1.0000x reference)
//
#include <hip/hip_runtime.h>
#include <math.h>

#define BB 4
#define CC 64
#define DI 128
#define NS 16
#define LL 9216
#define GCH 96
#define LCH 96
#define NT (LL / 64)   // 144 l-tiles per batch

// ---------------- instance-norm moments per (b,c) ----------------
__global__ __launch_bounds__(256) void k_stats(const float* __restrict__ p,
                                               float* __restrict__ stats) {
  int bc = blockIdx.x;  // 0..255
  const float* row = p + (size_t)bc * LL;
  float s = 0.f, s2 = 0.f;
  for (int i = threadIdx.x; i < LL; i += 256) {
    float v = row[i];
    s += v; s2 += v * v;
  }
  #pragma unroll
  for (int o = 32; o > 0; o >>= 1) {
    s += __shfl_down(s, o);
    s2 += __shfl_down(s2, o);
  }
  __shared__ float red[8];
  int w = threadIdx.x >> 6;
  if ((threadIdx.x & 63) == 0) { red[w] = s; red[4 + w] = s2; }
  __syncthreads();
  if (threadIdx.x == 0) {
    float S = red[0] + red[1] + red[2] + red[3];
    float S2 = red[4] + red[5] + red[6] + red[7];
    float m = S * (1.f / LL);
    float var = S2 * (1.f / LL) - m * m;
    stats[bc * 2] = m;
    stats[bc * 2 + 1] = rsqrtf(var + 1e-5f);
  }
}

// ------- transpose planar [b][c][l] -> [b][l][c], IN+relu, then LayerNorm -------
__global__ __launch_bounds__(256) void k_transln(const float* __restrict__ p,
                                                 const float* __restrict__ stats,
                                                 const float* __restrict__ g,
                                                 const float* __restrict__ be,
                                                 float* __restrict__ xf,
                                                 float* __restrict__ xn) {
  int b = blockIdx.x / NT;
  int l0 = (blockIdx.x % NT) * 64;
  __shared__ float T[64][65];
  int li = threadIdx.x & 63;
  int c0 = threadIdx.x >> 6;
  #pragma unroll
  for (int j = 0; j < 16; ++j) {
    int c = c0 * 16 + j;
    float m = stats[(b * CC + c) * 2];
    float rs = stats[(b * CC + c) * 2 + 1];
    float v = p[((size_t)(b * CC + c)) * LL + l0 + li];
    T[li][c] = fmaxf((v - m) * rs, 0.f);   // IN + relu
  }
  __syncthreads();
  int lane = threadIdx.x & 63;
  int w = threadIdx.x >> 6;
  float gv = g[lane], bv = be[lane];
  for (int j = 0; j < 16; ++j) {
    int row = w * 16 + j;
    float v = T[row][lane];
    float s = v, s2 = v * v;
    #pragma unroll
    for (int o = 32; o > 0; o >>= 1) { s += __shfl_xor(s, o); s2 += __shfl_xor(s2, o); }
    float m = s * (1.f / 64.f);
    float var = s2 * (1.f / 64.f) - m * m;
    float rs = rsqrtf(var + 1e-5f);
    size_t off = ((size_t)b * LL + l0 + row) * CC + lane;
    xf[off] = v;
    xn[off] = (v - m) * rs * gv + bv;
  }
}

// ---------------- in-proj: xz = xn @ in_w^T ; split xin / z ----------------
__global__ __launch_bounds__(256) void k_inproj(const float* __restrict__ xn,
                                                const float* __restrict__ w,
                                                float* __restrict__ xin,
                                                float* __restrict__ z) {
  int r0 = blockIdx.x * 64;
  __shared__ float X[64][68];
  __shared__ float Wt[64][68];
  int tid = threadIdx.x;
  for (int j = 0; j < 4; ++j) {
    int it = tid + 256 * j;
    int r = it >> 4, c4 = it & 15;
    *(float4*)&X[r][c4 * 4] = *(const float4*)&xn[(size_t)(r0 + r) * CC + c4 * 4];
  }
  int tc = tid & 15, tr = tid >> 4;
  for (int ob = 0; ob < 4; ++ob) {
    __syncthreads();
    for (int j = 0; j < 4; ++j) {
      int it = tid + 256 * j;
      int r = it >> 4, c4 = it & 15;
      *(float4*)&Wt[r][c4 * 4] = *(const float4*)&w[(size_t)(ob * 64 + r) * CC + c4 * 4];
    }
    __syncthreads();
    float acc[4][4] = {{0.f}};
    for (int k4 = 0; k4 < 16; ++k4) {
      float4 xa[4], wb[4];
      #pragma unroll
      for (int i = 0; i < 4; ++i) xa[i] = *(float4*)&X[tr * 4 + i][k4 * 4];
      #pragma unroll
      for (int i = 0; i < 4; ++i) wb[i] = *(float4*)&Wt[tc * 4 + i][k4 * 4];
      #pragma unroll
      for (int i = 0; i < 4; ++i)
        #pragma unroll
        for (int q = 0; q < 4; ++q)
          acc[i][q] += xa[i].x * wb[q].x + xa[i].y * wb[q].y +
                       xa[i].z * wb[q].z + xa[i].w * wb[q].w;
    }
    float* dst = (ob < 2) ? xin : z;
    int cb = (ob & 1) * 64;
    for (int i = 0; i < 4; ++i) {
      float4 o = make_float4(acc[i][0], acc[i][1], acc[i][2], acc[i][3]);
      *(float4*)&dst[(size_t)(r0 + tr * 4 + i) * DI + cb + tc * 4] = o;
    }
  }
}

// ---------------- depthwise causal conv (K=4) + SiLU ----------------
__global__ __launch_bounds__(256) void k_conv(const float* __restrict__ xin,
                                              const float* __restrict__ cw,
                                              const float* __restrict__ cb,
                                              float* __restrict__ xc) {
  int idx = blockIdx.x * 256 + threadIdx.x;   // < BB*LL*DI
  int d = idx & (DI - 1);
  int row = idx >> 7;
  int l = row % LL;
  float acc = cb[d];
  #pragma unroll
  for (int k = 0; k < 4; ++k) {
    int lk = l - 3 + k;
    if (lk >= 0) acc += xin[(size_t)(row - 3 + k) * DI + d] * cw[d * 4 + k];
  }
  xc[idx] = acc / (1.f + __expf(-acc));   // silu
}

// ---------------- x-proj (36 outs, K=128) + dt-proj + softplus ----------------
__global__ __launch_bounds__(256) void k_xpdt(const float* __restrict__ xc,
                                              const float* __restrict__ xpw,
                                              const float* __restrict__ dtw,
                                              const float* __restrict__ dtb,
                                              float* __restrict__ dt,
                                              float* __restrict__ Bm,
                                              float* __restrict__ Cm) {
  int r0 = blockIdx.x * 64;
  __shared__ float X[64][68];
  __shared__ float W[36][68];
  __shared__ float DBL[64][37];
  __shared__ float DTW[128 * 5];
  int tid = threadIdx.x;
  int row = tid >> 2, q = tid & 3;
  float acc[9];
  #pragma unroll
  for (int j = 0; j < 9; ++j) acc[j] = 0.f;
  for (int kh = 0; kh < 2; ++kh) {
    __syncthreads();
    for (int j = 0; j < 4; ++j) {
      int it = tid + 256 * j;
      int r = it >> 4, c4 = it & 15;
      *(float4*)&X[r][c4 * 4] = *(const float4*)&xc[(size_t)(r0 + r) * DI + kh * 64 + c4 * 4];
    }
    for (int j = 0; j < 3; ++j) {
      int it = tid + 256 * j;
      if (it < 576) {
        int r = it >> 4, c4 = it & 15;
        *(float4*)&W[r][c4 * 4] = *(const float4*)&xpw[(size_t)r * DI + kh * 64 + c4 * 4];
      }
    }
    __syncthreads();
    for (int k4 = 0; k4 < 16; ++k4) {
      float4 xv = *(float4*)&X[row][k4 * 4];
      #pragma unroll
      for (int j = 0; j < 9; ++j) {
        float4 wv = *(float4*)&W[q * 9 + j][k4 * 4];
        acc[j] += xv.x * wv.x + xv.y * wv.y + xv.z * wv.z + xv.w * wv.w;
      }
    }
  }
  #pragma unroll
  for (int j = 0; j < 2; ++j) {
    int it = tid + 256 * j;   // 512 dt_w entries
    DTW[(it >> 2) * 5 + (it & 3)] = dtw[it];
  }
  #pragma unroll
  for (int j = 0; j < 9; ++j) DBL[row][q * 9 + j] = acc[j];
  __syncthreads();
  #pragma unroll
  for (int j = 0; j < 4; ++j) {
    int it = tid + 256 * j;   // < 1024
    int r = it >> 4, n = it & 15;
    size_t off = (size_t)(r0 + r) * NS + n;
    Bm[off] = DBL[r][4 + n];
    Cm[off] = DBL[r][20 + n];
  }
  #pragma unroll
  for (int j = 0; j < 32; ++j) {
    int it = tid + 256 * j;   // < 8192
    int r = it >> 7, d = it & 127;
    float v = dtb[d] + DBL[r][0] * DTW[d * 5] + DBL[r][1] * DTW[d * 5 + 1]
            + DBL[r][2] * DTW[d * 5 + 2] + DBL[r][3] * DTW[d * 5 + 3];
    dt[(size_t)(r0 + r) * DI + d] = fmaxf(v, 0.f) + log1pf(__expf(-fabsf(v)));
  }
}

// ---------------- scan phase 1: per-chunk local scan ----------------
__global__ __launch_bounds__(256) void k_scan1(const float* __restrict__ dt,
                                               const float* __restrict__ xc,
                                               const float* __restrict__ Bm,
                                               const float* __restrict__ Alog,
                                               float* __restrict__ ap,
                                               float* __restrict__ hl) {
  int dblk = blockIdx.x & 7;
  int g = (blockIdx.x >> 3) % GCH;
  int b = (blockIdx.x >> 3) / GCH;
  int t = threadIdx.x;
  int dl = t >> 4, n = t & 15;
  int d = dblk * 16 + dl;
  float A = -__expf(Alog[d * NS + n]);
  float h = 0.f, apv = 1.f;
  __shared__ float dts[16][17], xcs[16][17], bms[16][17];
  int l0 = g * LCH;
  int li2 = t >> 4, j2 = t & 15;
  for (int sb = 0; sb < LCH / 16; ++sb) {
    __syncthreads();
    size_t rowb = (size_t)b * LL + l0 + sb * 16 + li2;
    dts[li2][j2] = dt[rowb * DI + dblk * 16 + j2];
    xcs[li2][j2] = xc[rowb * DI + dblk * 16 + j2];
    bms[li2][j2] = Bm[rowb * NS + j2];
    __syncthreads();
    #pragma unroll
    for (int li = 0; li < 16; ++li) {
      float dtv = dts[li][dl];
      float a = __expf(dtv * A);
      float bb = dtv * bms[li][n] * xcs[li][dl];
      h = a * h + bb;
      apv *= a;
    }
  }
  size_t idx = (size_t)g * 8192 + b * 2048 + dblk * 256 + t;
  ap[idx] = apv;
  hl[idx] = h;
}

// ---------------- scan phase 2: cross-chunk carry ----------------
__global__ __launch_bounds__(256) void k_scan2(const float* __restrict__ ap,
                                               const float* __restrict__ hl,
                                               float* __restrict__ hi) {
  int seq = blockIdx.x * 256 + threadIdx.x;  // < 8192
  float h = 0.f;
  #pragma unroll 8
  for (int g = 0; g < GCH; ++g) {
    hi[(size_t)g * 8192 + seq] = h;
    h = ap[(size_t)g * 8192 + seq] * h + hl[(size_t)g * 8192 + seq];
  }
}

// ------- scan phase 3: replay with carry, fuse einsum-over-N, +D*xc, *silu(z) -------
__global__ __launch_bounds__(256) void k_scan3(const float* dt_in,   // aliases y!
                                               const float* __restrict__ xc,
                                               const float* __restrict__ Bm,
                                               const float* __restrict__ Cm,
                                               const float* __restrict__ z,
                                               const float* __restrict__ Alog,
                                               const float* __restrict__ Dp,
                                               const float* __restrict__ hi,
                                               float* y) {
  int dblk = blockIdx.x & 7;
  int g = (blockIdx.x >> 3) % GCH;
  int b = (blockIdx.x >> 3) / GCH;
  int t = threadIdx.x;
  int dl = t >> 4, n = t & 15;
  int d = dblk * 16 + dl;
  float A = -__expf(Alog[d * NS + n]);
  float Dv = Dp[d];
  float h = hi[(size_t)g * 8192 + b * 2048 + dblk * 256 + t];
  __shared__ float dts[16][17], xcs[16][17], bms[16][17], cms[16][17], zs[16][17];
  __shared__ float ys[16][16];
  int l0 = g * LCH;
  int li2 = t >> 4, j2 = t & 15;
  for (int sb = 0; sb < LCH / 16; ++sb) {
    __syncthreads();
    size_t rowb = (size_t)b * LL + l0 + sb * 16 + li2;
    dts[li2][j2] = dt_in[rowb * DI + dblk * 16 + j2];
    xcs[li2][j2] = xc[rowb * DI + dblk * 16 + j2];
    bms[li2][j2] = Bm[rowb * NS + j2];
    cms[li2][j2] = Cm[rowb * NS + j2];
    zs[li2][j2] = z[rowb * DI + dblk * 16 + j2];
    __syncthreads();
    #pragma unroll
    for (int li = 0; li < 16; ++li) {
      float dtv = dts[li][dl];
      float xcv = xcs[li][dl];
      float a = __expf(dtv * A);
      float bb = dtv * bms[li][n] * xcv;
      h = a * h + bb;
      float p = h * cms[li][n];
      p += __shfl_xor(p, 1);
      p += __shfl_xor(p, 2);
      p += __shfl_xor(p, 4);
      p += __shfl_xor(p, 8);
      if (n == 0) {
        float zv = zs[li][dl];
        ys[li][dl] = (p + Dv * xcv) * (zv / (1.f + __expf(-zv)));
      }
    }
    __syncthreads();
    y[rowb * DI + dblk * 16 + j2] = ys[li2][j2];
  }
}

// ---------------- out-proj (K=128) + skip*xf ----------------
__global__ __launch_bounds__(256) void k_outproj(const float* __restrict__ y,
                                                 const float* __restrict__ ow,
                                                 const float* __restrict__ xf,
                                                 const float* __restrict__ skipv,
                                                 float* __restrict__ tmp) {
  int r0 = blockIdx.x * 64;
  __shared__ float X[64][68];
  __shared__ float Wt[64][68];
  int tid = threadIdx.x;
  int tc = tid & 15, tr = tid >> 4;
  float acc[4][4] = {{0.f}};
  for (int kh = 0; kh < 2; ++kh) {
    __syncthreads();
    for (int j = 0; j < 4; ++j) {
      int it = tid + 256 * j;
      int r = it >> 4, c4 = it & 15;
      *(float4*)&X[r][c4 * 4] = *(const float4*)&y[(size_t)(r0 + r) * DI + kh * 64 + c4 * 4];
      *(float4*)&Wt[r][c4 * 4] = *(const float4*)&ow[(size_t)r * DI + kh * 64 + c4 * 4];
    }
    __syncthreads();
    for (int k4 = 0; k4 < 16; ++k4) {
      float4 xa[4], wb[4];
      #pragma unroll
      for (int i = 0; i < 4; ++i) xa[i] = *(float4*)&X[tr * 4 + i][k4 * 4];
      #pragma unroll
      for (int i = 0; i < 4; ++i) wb[i] = *(float4*)&Wt[tc * 4 + i][k4 * 4];
      #pragma unroll
      for (int i = 0; i < 4; ++i)
        #pragma unroll
        for (int q = 0; q < 4; ++q)
          acc[i][q] += xa[i].x * wb[q].x + xa[i].y * wb[q].y +
                       xa[i].z * wb[q].z + xa[i].w * wb[q].w;
    }
  }
  float sk = skipv[0];
  for (int i = 0; i < 4; ++i) {
    size_t off = (size_t)(r0 + tr * 4 + i) * CC + tc * 4;
    float4 xfv = *(const float4*)&xf[off];
    float4 o = make_float4(acc[i][0] + sk * xfv.x, acc[i][1] + sk * xfv.y,
                           acc[i][2] + sk * xfv.z, acc[i][3] + sk * xfv.w);
    *(float4*)&tmp[off] = o;
  }
}

// ---------------- pr-proj (K=64) + bias (+identity), transposed planar write ----------------
__global__ __launch_bounds__(256) void k_prproj(const float* __restrict__ tmp,
                                                const float* __restrict__ pw,
                                                const float* __restrict__ pb,
                                                const float* __restrict__ ident,
                                                float* __restrict__ dst, int addid) {
  int b = blockIdx.x / NT;
  int l0 = (blockIdx.x % NT) * 64;
  __shared__ float T[64][68];
  __shared__ float Wt[64][68];
  int tid = threadIdx.x;
  for (int j = 0; j < 4; ++j) {
    int it = tid + 256 * j;
    int r = it >> 4, c4 = it & 15;
    *(float4*)&T[r][c4 * 4] = *(const float4*)&tmp[((size_t)b * LL + l0 + r) * CC + c4 * 4];
    *(float4*)&Wt[r][c4 * 4] = *(const float4*)&pw[(size_t)r * CC + c4 * 4];
  }
  __syncthreads();
  int tl = tid & 15, tc = tid >> 4;
  float acc[4][4] = {{0.f}};   // [ci][v]
  for (int k4 = 0; k4 < 16; ++k4) {
    float4 ta[4], wb[4];
    #pragma unroll
    for (int v = 0; v < 4; ++v) ta[v] = *(float4*)&T[tl * 4 + v][k4 * 4];
    #pragma unroll
    for (int ci = 0; ci < 4; ++ci) wb[ci] = *(float4*)&Wt[tc * 4 + ci][k4 * 4];
    #pragma unroll
    for (int ci = 0; ci < 4; ++ci)
      #pragma unroll
      for (int v = 0; v < 4; ++v)
        acc[ci][v] += wb[ci].x * ta[v].x + wb[ci].y * ta[v].y +
                      wb[ci].z * ta[v].z + wb[ci].w * ta[v].w;
  }
  for (int ci = 0; ci < 4; ++ci) {
    int c = tc * 4 + ci;
    float pbv = pb[c];
    size_t off = ((size_t)(b * CC + c)) * LL + l0 + tl * 4;
    float4 o = make_float4(acc[ci][0] + pbv, acc[ci][1] + pbv,
                           acc[ci][2] + pbv, acc[ci][3] + pbv);
    if (addid) {
      float4 iv = *(const float4*)&ident[off];
      o.x += iv.x; o.y += iv.y; o.z += iv.z; o.w += iv.w;
    }
    *(float4*)&dst[off] = o;
  }
}

extern "C" void kernel_launch(void* const* d_in, const int* in_sizes, int n_in,
                              void* d_out, int out_size, void* d_ws, size_t ws_size,
                              hipStream_t stream) {
  const float* x = (const float*)d_in[0];
  float* ws = (float*)d_ws;
  float* stats = ws;                       //    1024
  float* xf    = ws + 1024;                // 2359296
  float* xn    = xf + 2359296;             // 2359296  (later reused as `tmp`)
  float* zbuf  = xn + 2359296;             // 4718592  (layer output `inter` aliases this)
  float* xcb   = zbuf + 4718592;           // 4718592
  float* dtb   = xcb + 4718592;            // 4718592  (xin -> dt -> y, sequential reuse)
  float* Bmb   = dtb + 4718592;            //  589824
  float* Cmb   = Bmb + 589824;             //  589824
  float* apb   = Cmb + 589824;             //  786432
  float* hlb   = apb + 786432;             //  786432
  float* hib   = hlb + 786432;             //  786432
  float* inter = zbuf;                     // alias: dead z of layer N == input of layer N+1
  float* outp  = (float*)d_out;

  const float* cur = x;
  for (int layer = 0; layer < 2; ++layer) {
    const int p0 = 1 + 14 * layer;
    const float* ln_g   = (const float*)d_in[p0 + 0];
    const float* ln_b   = (const float*)d_in[p0 + 1];
    const float* in_w   = (const float*)d_in[p0 + 2];
    const float* conv_w = (const float*)d_in[p0 + 3];
    const float* conv_b = (const float*)d_in[p0 + 4];
    const float* xp_w   = (const float*)d_in[p0 + 5];
    const float* dt_w   = (const float*)d_in[p0 + 6];
    const float* dt_b   = (const float*)d_in[p0 + 7];
    const float* A_log  = (const float*)d_in[p0 + 8];
    const float* Dp     = (const float*)d_in[p0 + 9];
    const float* out_w  = (const float*)d_in[p0 + 10];
    const float* skip   = (const float*)d_in[p0 + 11];
    const float* pr_w   = (const float*)d_in[p0 + 12];
    const float* pr_b   = (const float*)d_in[p0 + 13];
    float* dst = (layer == 0) ? inter : outp;

    k_stats  <<<BB * CC, 256, 0, stream>>>(cur, stats);
    k_transln<<<BB * NT, 256, 0, stream>>>(cur, stats, ln_g, ln_b, xf, xn);
    k_inproj <<<(BB * LL) / 64, 256, 0, stream>>>(xn, in_w, dtb /*xin*/, zbuf);
    k_conv   <<<(BB * LL * DI) / 256, 256, 0, stream>>>(dtb /*xin*/, conv_w, conv_b, xcb);
    k_xpdt   <<<(BB * LL) / 64, 256, 0, stream>>>(xcb, xp_w, dt_w, dt_b, dtb /*dt*/, Bmb, Cmb);
    k_scan1  <<<BB * GCH * 8, 256, 0, stream>>>(dtb, xcb, Bmb, A_log, apb, hlb);
    k_scan2  <<<32, 256, 0, stream>>>(apb, hlb, hib);
    k_scan3  <<<BB * GCH * 8, 256, 0, stream>>>(dtb, xcb, Bmb, Cmb, zbuf, A_log, Dp, hib,
                                                dtb /*y aliases dt, safe per-block*/);
    k_outproj<<<(BB * LL) / 64, 256, 0, stream>>>(dtb /*y*/, out_w, xf, skip, xn /*tmp*/);
    k_prproj <<<BB * NT, 256, 0, stream>>>(xn /*tmp*/, pr_w, pr_b, x, dst, layer);
    cur = inter;
  }
}

// Round 2
// 441.009 us; speedup vs baseline: 1.2567x; 1.2567x over previous
//
#include <hip/hip_runtime.h>
#include <math.h>

#define BB 4
#define CC 64
#define DI 128
#define NS 16
#define LL 9216
#define NT (LL / 64)   // 144 l-tiles per batch

// scan decomposition
#define GCH 288        // chunks
#define LCH 32         // steps per chunk (GCH*LCH == LL)
#define NSEQ 8192      // B*DI*NS independent sequences
#define NG 9           // groups of chunks for the 3-level chunk scan
#define GS 32          // chunks per group (NG*GS == GCH)

// ---------------- instance-norm moments per (b,c) ----------------
__global__ __launch_bounds__(256) void k_stats(const float* __restrict__ p,
                                               float* __restrict__ stats) {
  int bc = blockIdx.x;  // 0..255
  const float* row = p + (size_t)bc * LL;
  float s = 0.f, s2 = 0.f;
  for (int i = threadIdx.x; i < LL; i += 256) {
    float v = row[i];
    s += v; s2 += v * v;
  }
  #pragma unroll
  for (int o = 32; o > 0; o >>= 1) {
    s += __shfl_down(s, o);
    s2 += __shfl_down(s2, o);
  }
  __shared__ float red[8];
  int w = threadIdx.x >> 6;
  if ((threadIdx.x & 63) == 0) { red[w] = s; red[4 + w] = s2; }
  __syncthreads();
  if (threadIdx.x == 0) {
    float S = red[0] + red[1] + red[2] + red[3];
    float S2 = red[4] + red[5] + red[6] + red[7];
    float m = S * (1.f / LL);
    float var = S2 * (1.f / LL) - m * m;
    stats[bc * 2] = m;
    stats[bc * 2 + 1] = rsqrtf(var + 1e-5f);
  }
}

// ------- transpose planar [b][c][l] -> [b][l][c], IN+relu, then LayerNorm -------
__global__ __launch_bounds__(256) void k_transln(const float* __restrict__ p,
                                                 const float* __restrict__ stats,
                                                 const float* __restrict__ g,
                                                 const float* __restrict__ be,
                                                 float* __restrict__ xf,
                                                 float* __restrict__ xn) {
  int b = blockIdx.x / NT;
  int l0 = (blockIdx.x % NT) * 64;
  __shared__ float T[64][65];
  int li = threadIdx.x & 63;
  int c0 = threadIdx.x >> 6;
  #pragma unroll
  for (int j = 0; j < 16; ++j) {
    int c = c0 * 16 + j;
    float m = stats[(b * CC + c) * 2];
    float rs = stats[(b * CC + c) * 2 + 1];
    float v = p[((size_t)(b * CC + c)) * LL + l0 + li];
    T[li][c] = fmaxf((v - m) * rs, 0.f);   // IN + relu
  }
  __syncthreads();
  int lane = threadIdx.x & 63;
  int w = threadIdx.x >> 6;
  float gv = g[lane], bv = be[lane];
  for (int j = 0; j < 16; ++j) {
    int row = w * 16 + j;
    float v = T[row][lane];
    float s = v, s2 = v * v;
    #pragma unroll
    for (int o = 32; o > 0; o >>= 1) { s += __shfl_xor(s, o); s2 += __shfl_xor(s2, o); }
    float m = s * (1.f / 64.f);
    float var = s2 * (1.f / 64.f) - m * m;
    float rs = rsqrtf(var + 1e-5f);
    size_t off = ((size_t)b * LL + l0 + row) * CC + lane;
    xf[off] = v;
    xn[off] = (v - m) * rs * gv + bv;
  }
}

// ---------------- in-proj: xz = xn @ in_w^T ; split xin / z ----------------
__global__ __launch_bounds__(256) void k_inproj(const float* __restrict__ xn,
                                                const float* __restrict__ w,
                                                float* __restrict__ xin,
                                                float* __restrict__ z) {
  int r0 = blockIdx.x * 64;
  __shared__ float X[64][68];
  __shared__ float Wt[64][68];
  int tid = threadIdx.x;
  for (int j = 0; j < 4; ++j) {
    int it = tid + 256 * j;
    int r = it >> 4, c4 = it & 15;
    *(float4*)&X[r][c4 * 4] = *(const float4*)&xn[(size_t)(r0 + r) * CC + c4 * 4];
  }
  int tc = tid & 15, tr = tid >> 4;
  for (int ob = 0; ob < 4; ++ob) {
    __syncthreads();
    for (int j = 0; j < 4; ++j) {
      int it = tid + 256 * j;
      int r = it >> 4, c4 = it & 15;
      *(float4*)&Wt[r][c4 * 4] = *(const float4*)&w[(size_t)(ob * 64 + r) * CC + c4 * 4];
    }
    __syncthreads();
    float acc[4][4] = {{0.f}};
    for (int k4 = 0; k4 < 16; ++k4) {
      float4 xa[4], wb[4];
      #pragma unroll
      for (int i = 0; i < 4; ++i) xa[i] = *(float4*)&X[tr * 4 + i][k4 * 4];
      #pragma unroll
      for (int i = 0; i < 4; ++i) wb[i] = *(float4*)&Wt[tc * 4 + i][k4 * 4];
      #pragma unroll
      for (int i = 0; i < 4; ++i)
        #pragma unroll
        for (int q = 0; q < 4; ++q)
          acc[i][q] += xa[i].x * wb[q].x + xa[i].y * wb[q].y +
                       xa[i].z * wb[q].z + xa[i].w * wb[q].w;
    }
    float* dst = (ob < 2) ? xin : z;
    int cb = (ob & 1) * 64;
    for (int i = 0; i < 4; ++i) {
      float4 o = make_float4(acc[i][0], acc[i][1], acc[i][2], acc[i][3]);
      *(float4*)&dst[(size_t)(r0 + tr * 4 + i) * DI + cb + tc * 4] = o;
    }
  }
}

// ---------------- depthwise causal conv (K=4) + SiLU ----------------
__global__ __launch_bounds__(256) void k_conv(const float* __restrict__ xin,
                                              const float* __restrict__ cw,
                                              const float* __restrict__ cb,
                                              float* __restrict__ xc) {
  int idx = blockIdx.x * 256 + threadIdx.x;   // < BB*LL*DI
  int d = idx & (DI - 1);
  int row = idx >> 7;
  int l = row % LL;
  float acc = cb[d];
  #pragma unroll
  for (int k = 0; k < 4; ++k) {
    int lk = l - 3 + k;
    if (lk >= 0) acc += xin[(size_t)(row - 3 + k) * DI + d] * cw[d * 4 + k];
  }
  xc[idx] = acc / (1.f + __expf(-acc));   // silu
}

// ---------------- x-proj (36 outs, K=128) + dt-proj + softplus ----------------
__global__ __launch_bounds__(256) void k_xpdt(const float* __restrict__ xc,
                                              const float* __restrict__ xpw,
                                              const float* __restrict__ dtw,
                                              const float* __restrict__ dtb,
                                              float* __restrict__ dt,
                                              float* __restrict__ Bm,
                                              float* __restrict__ Cm) {
  int r0 = blockIdx.x * 64;
  __shared__ float X[64][68];
  __shared__ float W[36][68];
  __shared__ float DBL[64][37];
  __shared__ float DTW[128 * 5];
  int tid = threadIdx.x;
  int row = tid >> 2, q = tid & 3;
  float acc[9];
  #pragma unroll
  for (int j = 0; j < 9; ++j) acc[j] = 0.f;
  for (int kh = 0; kh < 2; ++kh) {
    __syncthreads();
    for (int j = 0; j < 4; ++j) {
      int it = tid + 256 * j;
      int r = it >> 4, c4 = it & 15;
      *(float4*)&X[r][c4 * 4] = *(const float4*)&xc[(size_t)(r0 + r) * DI + kh * 64 + c4 * 4];
    }
    for (int j = 0; j < 3; ++j) {
      int it = tid + 256 * j;
      if (it < 576) {
        int r = it >> 4, c4 = it & 15;
        *(float4*)&W[r][c4 * 4] = *(const float4*)&xpw[(size_t)r * DI + kh * 64 + c4 * 4];
      }
    }
    __syncthreads();
    for (int k4 = 0; k4 < 16; ++k4) {
      float4 xv = *(float4*)&X[row][k4 * 4];
      #pragma unroll
      for (int j = 0; j < 9; ++j) {
        float4 wv = *(float4*)&W[q * 9 + j][k4 * 4];
        acc[j] += xv.x * wv.x + xv.y * wv.y + xv.z * wv.z + xv.w * wv.w;
      }
    }
  }
  #pragma unroll
  for (int j = 0; j < 2; ++j) {
    int it = tid + 256 * j;   // 512 dt_w entries
    DTW[(it >> 2) * 5 + (it & 3)] = dtw[it];
  }
  #pragma unroll
  for (int j = 0; j < 9; ++j) DBL[row][q * 9 + j] = acc[j];
  __syncthreads();
  #pragma unroll
  for (int j = 0; j < 4; ++j) {
    int it = tid + 256 * j;   // < 1024
    int r = it >> 4, n = it & 15;
    size_t off = (size_t)(r0 + r) * NS + n;
    Bm[off] = DBL[r][4 + n];
    Cm[off] = DBL[r][20 + n];
  }
  #pragma unroll
  for (int j = 0; j < 32; ++j) {
    int it = tid + 256 * j;   // < 8192
    int r = it >> 7, d = it & 127;
    float v = dtb[d] + DBL[r][0] * DTW[d * 5] + DBL[r][1] * DTW[d * 5 + 1]
            + DBL[r][2] * DTW[d * 5 + 2] + DBL[r][3] * DTW[d * 5 + 3];
    dt[(size_t)(r0 + r) * DI + d] = fmaxf(v, 0.f) + log1pf(__expf(-fabsf(v)));
  }
}

// ---------------- scan phase 1: per-chunk local scan, N states in registers ----------------
__global__ __launch_bounds__(128) void k_scanA(const float* __restrict__ dt,
                                               const float* __restrict__ xc,
                                               const float* __restrict__ Bm,
                                               const float* __restrict__ Alog,
                                               float* __restrict__ ap,
                                               float* __restrict__ hl) {
  int g = blockIdx.x % GCH;
  int b = blockIdx.x / GCH;
  int d = threadIdx.x;   // 0..127
  float A[16];
  #pragma unroll
  for (int j = 0; j < 4; ++j) {
    float4 al = *(const float4*)&Alog[d * NS + j * 4];
    A[j * 4 + 0] = -__expf(al.x);
    A[j * 4 + 1] = -__expf(al.y);
    A[j * 4 + 2] = -__expf(al.z);
    A[j * 4 + 3] = -__expf(al.w);
  }
  __shared__ float Bms[LCH * NS];     // 2 KB
  {
    int idx = threadIdx.x * 4;        // 512 floats total
    int l = idx >> 4, n = idx & 15;
    *(float4*)&Bms[idx] = *(const float4*)&Bm[((size_t)b * LL + g * LCH + l) * NS + n];
  }
  __syncthreads();
  float h[16];
  #pragma unroll
  for (int n = 0; n < 16; ++n) h[n] = 0.f;
  float dtsum = 0.f;
  const float* dtp = dt + ((size_t)b * LL + g * LCH) * DI + d;
  const float* xcp = xc + ((size_t)b * LL + g * LCH) * DI + d;
  #pragma unroll 4
  for (int l = 0; l < LCH; ++l) {
    float dtv = dtp[(size_t)l * DI];
    float xcv = xcp[(size_t)l * DI];
    float dx = dtv * xcv;
    dtsum += dtv;
    float4 b0 = *(float4*)&Bms[l * 16];
    float4 b1 = *(float4*)&Bms[l * 16 + 4];
    float4 b2 = *(float4*)&Bms[l * 16 + 8];
    float4 b3 = *(float4*)&Bms[l * 16 + 12];
    float a[16];
    #pragma unroll
    for (int n = 0; n < 16; ++n) a[n] = __expf(dtv * A[n]);
    h[0]  = a[0]  * h[0]  + dx * b0.x;  h[1]  = a[1]  * h[1]  + dx * b0.y;
    h[2]  = a[2]  * h[2]  + dx * b0.z;  h[3]  = a[3]  * h[3]  + dx * b0.w;
    h[4]  = a[4]  * h[4]  + dx * b1.x;  h[5]  = a[5]  * h[5]  + dx * b1.y;
    h[6]  = a[6]  * h[6]  + dx * b1.z;  h[7]  = a[7]  * h[7]  + dx * b1.w;
    h[8]  = a[8]  * h[8]  + dx * b2.x;  h[9]  = a[9]  * h[9]  + dx * b2.y;
    h[10] = a[10] * h[10] + dx * b2.z;  h[11] = a[11] * h[11] + dx * b2.w;
    h[12] = a[12] * h[12] + dx * b3.x;  h[13] = a[13] * h[13] + dx * b3.y;
    h[14] = a[14] * h[14] + dx * b3.z;  h[15] = a[15] * h[15] + dx * b3.w;
  }
  size_t o = (size_t)g * NSEQ + ((size_t)b * DI + d) * NS;
  #pragma unroll
  for (int j = 0; j < 4; ++j) {
    float4 av = make_float4(__expf(dtsum * A[j*4]), __expf(dtsum * A[j*4+1]),
                            __expf(dtsum * A[j*4+2]), __expf(dtsum * A[j*4+3]));
    *(float4*)&ap[o + j * 4] = av;
    *(float4*)&hl[o + j * 4] = make_float4(h[j*4], h[j*4+1], h[j*4+2], h[j*4+3]);
  }
}

// ---------------- scan phase 2a: per-group chunk aggregates ----------------
__global__ __launch_bounds__(256) void k_scan2a(const float* __restrict__ ap,
                                                const float* __restrict__ hl,
                                                float* __restrict__ gap,
                                                float* __restrict__ ghl) {
  int t = blockIdx.x * 256 + threadIdx.x;   // < NG*NSEQ
  int grp = t >> 13, seq = t & (NSEQ - 1);
  float A = 1.f, H = 0.f;
  int c0 = grp * GS;
  #pragma unroll 4
  for (int c = 0; c < GS; ++c) {
    float a = ap[(size_t)(c0 + c) * NSEQ + seq];
    float h = hl[(size_t)(c0 + c) * NSEQ + seq];
    H = a * H + h;
    A = a * A;
  }
  gap[t] = A;
  ghl[t] = H;
}

// ---------------- scan phase 2b: scan over groups ----------------
__global__ __launch_bounds__(256) void k_scan2b(const float* __restrict__ gap,
                                                const float* __restrict__ ghl,
                                                float* __restrict__ hig) {
  int seq = blockIdx.x * 256 + threadIdx.x;  // < NSEQ
  float h = 0.f;
  #pragma unroll
  for (int grp = 0; grp < NG; ++grp) {
    hig[grp * NSEQ + seq] = h;
    h = gap[grp * NSEQ + seq] * h + ghl[grp * NSEQ + seq];
  }
}

// ---------------- scan phase 2c: per-chunk carries (hi aliases ap!) ----------------
__global__ __launch_bounds__(256) void k_scan2c(const float* ap,   // == hi
                                                const float* __restrict__ hl,
                                                const float* __restrict__ hig,
                                                float* hi) {
  int t = blockIdx.x * 256 + threadIdx.x;   // < NG*NSEQ
  int grp = t >> 13, seq = t & (NSEQ - 1);
  float h = hig[t];
  int c0 = grp * GS;
  size_t idx = (size_t)c0 * NSEQ + seq;
  float a = ap[idx], bb = hl[idx];
  for (int c = 0; c < GS; ++c) {
    size_t nidx = idx + NSEQ;
    float an = 0.f, bn = 0.f;
    if (c + 1 < GS) { an = ap[nidx]; bn = hl[nidx]; }  // prefetch before clobber
    hi[idx] = h;                                        // overwrites ap[idx]
    h = a * h + bb;
    a = an; bb = bn; idx = nidx;
  }
}

// ------- scan phase 3: replay with carry; einsum-over-N in regs; +D*xc; *silu(z) -------
__global__ __launch_bounds__(128) void k_scanC(const float* dt_in,   // aliases y!
                                               const float* __restrict__ xc,
                                               const float* __restrict__ Bm,
                                               const float* __restrict__ Cm,
                                               const float* __restrict__ z,
                                               const float* __restrict__ Alog,
                                               const float* __restrict__ Dp,
                                               const float* __restrict__ hi,
                                               float* y) {
  int g = blockIdx.x % GCH;
  int b = blockIdx.x / GCH;
  int d = threadIdx.x;
  float A[16];
  #pragma unroll
  for (int j = 0; j < 4; ++j) {
    float4 al = *(const float4*)&Alog[d * NS + j * 4];
    A[j * 4 + 0] = -__expf(al.x);
    A[j * 4 + 1] = -__expf(al.y);
    A[j * 4 + 2] = -__expf(al.z);
    A[j * 4 + 3] = -__expf(al.w);
  }
  float Dv = Dp[d];
  __shared__ float Bms[LCH * NS];
  __shared__ float Cms[LCH * NS];
  {
    int idx = threadIdx.x * 4;
    int l = idx >> 4, n = idx & 15;
    size_t goff = ((size_t)b * LL + g * LCH + l) * NS + n;
    *(float4*)&Bms[idx] = *(const float4*)&Bm[goff];
    *(float4*)&Cms[idx] = *(const float4*)&Cm[goff];
  }
  __syncthreads();
  size_t o = (size_t)g * NSEQ + ((size_t)b * DI + d) * NS;
  float h[16];
  #pragma unroll
  for (int j = 0; j < 4; ++j) {
    float4 hv = *(const float4*)&hi[o + j * 4];
    h[j * 4 + 0] = hv.x; h[j * 4 + 1] = hv.y; h[j * 4 + 2] = hv.z; h[j * 4 + 3] = hv.w;
  }
  size_t base = ((size_t)b * LL + g * LCH) * DI + d;
  float dtv = dt_in[base], xcv = xc[base], zv = z[base];
  for (int l = 0; l < LCH; ++l) {
    int ln = (l + 1 < LCH) ? l + 1 : l;
    float dtn = dt_in[base + (size_t)ln * DI];   // prefetch next step
    float xcn = xc[base + (size_t)ln * DI];
    float zn  = z[base + (size_t)ln * DI];
    float4 b0 = *(float4*)&Bms[l * 16];
    float4 b1 = *(float4*)&Bms[l * 16 + 4];
    float4 b2 = *(float4*)&Bms[l * 16 + 8];
    float4 b3 = *(float4*)&Bms[l * 16 + 12];
    float4 c0 = *(float4*)&Cms[l * 16];
    float4 c1 = *(float4*)&Cms[l * 16 + 4];
    float4 c2 = *(float4*)&Cms[l * 16 + 8];
    float4 c3 = *(float4*)&Cms[l * 16 + 12];
    float a[16];
    #pragma unroll
    for (int n = 0; n < 16; ++n) a[n] = __expf(dtv * A[n]);
    float dx = dtv * xcv;
    float yv = Dv * xcv;
    h[0]  = a[0]  * h[0]  + dx * b0.x;  yv += h[0]  * c0.x;
    h[1]  = a[1]  * h[1]  + dx * b0.y;  yv += h[1]  * c0.y;
    h[2]  = a[2]  * h[2]  + dx * b0.z;  yv += h[2]  * c0.z;
    h[3]  = a[3]  * h[3]  + dx * b0.w;  yv += h[3]  * c0.w;
    h[4]  = a[4]  * h[4]  + dx * b1.x;  yv += h[4]  * c1.x;
    h[5]  = a[5]  * h[5]  + dx * b1.y;  yv += h[5]  * c1.y;
    h[6]  = a[6]  * h[6]  + dx * b1.z;  yv += h[6]  * c1.z;
    h[7]  = a[7]  * h[7]  + dx * b1.w;  yv += h[7]  * c1.w;
    h[8]  = a[8]  * h[8]  + dx * b2.x;  yv += h[8]  * c2.x;
    h[9]  = a[9]  * h[9]  + dx * b2.y;  yv += h[9]  * c2.y;
    h[10] = a[10] * h[10] + dx * b2.z;  yv += h[10] * c2.z;
    h[11] = a[11] * h[11] + dx * b2.w;  yv += h[11] * c2.w;
    h[12] = a[12] * h[12] + dx * b3.x;  yv += h[12] * c3.x;
    h[13] = a[13] * h[13] + dx * b3.y;  yv += h[13] * c3.y;
    h[14] = a[14] * h[14] + dx * b3.z;  yv += h[14] * c3.z;
    h[15] = a[15] * h[15] + dx * b3.w;  yv += h[15] * c3.w;
    float sg = zv / (1.f + __expf(-zv));
    y[base + (size_t)l * DI] = yv * sg;
    dtv = dtn; xcv = xcn; zv = zn;
  }
}

// ---------------- out-proj (K=128) + skip*xf ----------------
__global__ __launch_bounds__(256) void k_outproj(const float* __restrict__ y,
                                                 const float* __restrict__ ow,
                                                 const float* __restrict__ xf,
                                                 const float* __restrict__ skipv,
                                                 float* __restrict__ tmp) {
  int r0 = blockIdx.x * 64;
  __shared__ float X[64][68];
  __shared__ float Wt[64][68];
  int tid = threadIdx.x;
  int tc = tid & 15, tr = tid >> 4;
  float acc[4][4] = {{0.f}};
  for (int kh = 0; kh < 2; ++kh) {
    __syncthreads();
    for (int j = 0; j < 4; ++j) {
      int it = tid + 256 * j;
      int r = it >> 4, c4 = it & 15;
      *(float4*)&X[r][c4 * 4] = *(const float4*)&y[(size_t)(r0 + r) * DI + kh * 64 + c4 * 4];
      *(float4*)&Wt[r][c4 * 4] = *(const float4*)&ow[(size_t)r * DI + kh * 64 + c4 * 4];
    }
    __syncthreads();
    for (int k4 = 0; k4 < 16; ++k4) {
      float4 xa[4], wb[4];
      #pragma unroll
      for (int i = 0; i < 4; ++i) xa[i] = *(float4*)&X[tr * 4 + i][k4 * 4];
      #pragma unroll
      for (int i = 0; i < 4; ++i) wb[i] = *(float4*)&Wt[tc * 4 + i][k4 * 4];
      #pragma unroll
      for (int i = 0; i < 4; ++i)
        #pragma unroll
        for (int q = 0; q < 4; ++q)
          acc[i][q] += xa[i].x * wb[q].x + xa[i].y * wb[q].y +
                       xa[i].z * wb[q].z + xa[i].w * wb[q].w;
    }
  }
  float sk = skipv[0];
  for (int i = 0; i < 4; ++i) {
    size_t off = (size_t)(r0 + tr * 4 + i) * CC + tc * 4;
    float4 xfv = *(const float4*)&xf[off];
    float4 o = make_float4(acc[i][0] + sk * xfv.x, acc[i][1] + sk * xfv.y,
                           acc[i][2] + sk * xfv.z, acc[i][3] + sk * xfv.w);
    *(float4*)&tmp[off] = o;
  }
}

// ---------------- pr-proj (K=64) + bias (+identity), transposed planar write ----------------
__global__ __launch_bounds__(256) void k_prproj(const float* __restrict__ tmp,
                                                const float* __restrict__ pw,
                                                const float* __restrict__ pb,
                                                const float* __restrict__ ident,
                                                float* __restrict__ dst, int addid) {
  int b = blockIdx.x / NT;
  int l0 = (blockIdx.x % NT) * 64;
  __shared__ float T[64][68];
  __shared__ float Wt[64][68];
  int tid = threadIdx.x;
  for (int j = 0; j < 4; ++j) {
    int it = tid + 256 * j;
    int r = it >> 4, c4 = it & 15;
    *(float4*)&T[r][c4 * 4] = *(const float4*)&tmp[((size_t)b * LL + l0 + r) * CC + c4 * 4];
    *(float4*)&Wt[r][c4 * 4] = *(const float4*)&pw[(size_t)r * CC + c4 * 4];
  }
  __syncthreads();
  int tl = tid & 15, tc = tid >> 4;
  float acc[4][4] = {{0.f}};   // [ci][v]
  for (int k4 = 0; k4 < 16; ++k4) {
    float4 ta[4], wb[4];
    #pragma unroll
    for (int v = 0; v < 4; ++v) ta[v] = *(float4*)&T[tl * 4 + v][k4 * 4];
    #pragma unroll
    for (int ci = 0; ci < 4; ++ci) wb[ci] = *(float4*)&Wt[tc * 4 + ci][k4 * 4];
    #pragma unroll
    for (int ci = 0; ci < 4; ++ci)
      #pragma unroll
      for (int v = 0; v < 4; ++v)
        acc[ci][v] += wb[ci].x * ta[v].x + wb[ci].y * ta[v].y +
                      wb[ci].z * ta[v].z + wb[ci].w * ta[v].w;
  }
  for (int ci = 0; ci < 4; ++ci) {
    int c = tc * 4 + ci;
    float pbv = pb[c];
    size_t off = ((size_t)(b * CC + c)) * LL + l0 + tl * 4;
    float4 o = make_float4(acc[ci][0] + pbv, acc[ci][1] + pbv,
                           acc[ci][2] + pbv, acc[ci][3] + pbv);
    if (addid) {
      float4 iv = *(const float4*)&ident[off];
      o.x += iv.x; o.y += iv.y; o.z += iv.z; o.w += iv.w;
    }
    *(float4*)&dst[off] = o;
  }
}

extern "C" void kernel_launch(void* const* d_in, const int* in_sizes, int n_in,
                              void* d_out, int out_size, void* d_ws, size_t ws_size,
                              hipStream_t stream) {
  const float* x = (const float*)d_in[0];
  float* ws = (float*)d_ws;
  float* stats = ws;                       //    1024
  float* xf    = ws + 1024;                // 2359296
  float* xn    = xf + 2359296;             // 2359296  (ln-out -> hl -> tmp, sequential reuse)
  float* zbuf  = xn + 2359296;             // 4718592  (layer output `inter` aliases this)
  float* xcb   = zbuf + 4718592;           // 4718592
  float* dtb   = xcb + 4718592;            // 4718592  (xin -> dt -> y, sequential reuse)
  float* Bmb   = dtb + 4718592;            //  589824
  float* Cmb   = Bmb + 589824;             //  589824
  float* aphi  = Cmb + 589824;             // 2359296  (ap, then hi in-place)
  float* gapb  = aphi + 2359296;           //   73728
  float* ghlb  = gapb + 73728;             //   73728
  float* higb  = ghlb + 73728;             //   73728
  float* hlb   = xn;                       // alias: xn dead between inproj and outproj
  float* inter = zbuf;                     // alias: dead z of layer N == input of layer N+1
  float* outp  = (float*)d_out;

  const float* cur = x;
  for (int layer = 0; layer < 2; ++layer) {
    const int p0 = 1 + 14 * layer;
    const float* ln_g   = (const float*)d_in[p0 + 0];
    const float* ln_b   = (const float*)d_in[p0 + 1];
    const float* in_w   = (const float*)d_in[p0 + 2];
    const float* conv_w = (const float*)d_in[p0 + 3];
    const float* conv_b = (const float*)d_in[p0 + 4];
    const float* xp_w   = (const float*)d_in[p0 + 5];
    const float* dt_w   = (const float*)d_in[p0 + 6];
    const float* dt_b   = (const float*)d_in[p0 + 7];
    const float* A_log  = (const float*)d_in[p0 + 8];
    const float* Dp     = (const float*)d_in[p0 + 9];
    const float* out_w  = (const float*)d_in[p0 + 10];
    const float* skip   = (const float*)d_in[p0 + 11];
    const float* pr_w   = (const float*)d_in[p0 + 12];
    const float* pr_b   = (const float*)d_in[p0 + 13];
    float* dst = (layer == 0) ? inter : outp;

    k_stats  <<<BB * CC, 256, 0, stream>>>(cur, stats);
    k_transln<<<BB * NT, 256, 0, stream>>>(cur, stats, ln_g, ln_b, xf, xn);
    k_inproj <<<(BB * LL) / 64, 256, 0, stream>>>(xn, in_w, dtb /*xin*/, zbuf);
    k_conv   <<<(BB * LL * DI) / 256, 256, 0, stream>>>(dtb /*xin*/, conv_w, conv_b, xcb);
    k_xpdt   <<<(BB * LL) / 64, 256, 0, stream>>>(xcb, xp_w, dt_w, dt_b, dtb /*dt*/, Bmb, Cmb);
    k_scanA  <<<BB * GCH, 128, 0, stream>>>(dtb, xcb, Bmb, A_log, aphi /*ap*/, hlb);
    k_scan2a <<<(NG * NSEQ) / 256, 256, 0, stream>>>(aphi, hlb, gapb, ghlb);
    k_scan2b <<<NSEQ / 256, 256, 0, stream>>>(gapb, ghlb, higb);
    k_scan2c <<<(NG * NSEQ) / 256, 256, 0, stream>>>(aphi /*ap*/, hlb, higb, aphi /*hi*/);
    k_scanC  <<<BB * GCH, 128, 0, stream>>>(dtb, xcb, Bmb, Cmb, zbuf, A_log, Dp,
                                            aphi /*hi*/, dtb /*y, aliases dt (safe)*/);
    k_outproj<<<(BB * LL) / 64, 256, 0, stream>>>(dtb /*y*/, out_w, xf, skip, xn /*tmp*/);
    k_prproj <<<BB * NT, 256, 0, stream>>>(xn /*tmp*/, pr_w, pr_b, x, dst, layer);
    cur = inter;
  }
}

// Round 3
// 334.240 us; speedup vs baseline: 1.6581x; 1.3194x over previous
//
#include <hip/hip_runtime.h>
#include <math.h>

#define BB 4
#define CC 64
#define DI 128
#define NS 16
#define LL 9216
#define NT (LL / 64)

// scan decomposition
#define GCH 288
#define LCH 32
#define NSEQ 8192      // B*DI*NS
#define NG 9
#define GS 32

typedef __attribute__((ext_vector_type(8))) short bf16x8;
typedef __attribute__((ext_vector_type(4))) float fx4;
#define MFMA16 __builtin_amdgcn_mfma_f32_16x16x32_bf16

static __device__ __forceinline__ unsigned short f2b(float f) {
  unsigned u = __float_as_uint(f);
  u += 0x7fffu + ((u >> 16) & 1u);
  return (unsigned short)(u >> 16);
}
static __device__ __forceinline__ float b2f(unsigned short s) {
  return __uint_as_float(((unsigned)s) << 16);
}

// ---------------- weight bf16 conversion (once) ----------------
// per-layer bf16 pack: in_w[16384] | xp_w padded [48][128]=6144 | out_w[8192] | pr_w[4096]
__global__ __launch_bounds__(256) void k_cvt(const float* __restrict__ inw1, const float* __restrict__ xpw1,
                                             const float* __restrict__ ow1, const float* __restrict__ pw1,
                                             const float* __restrict__ inw2, const float* __restrict__ xpw2,
                                             const float* __restrict__ ow2, const float* __restrict__ pw2,
                                             unsigned short* __restrict__ wb) {
  int idx = blockIdx.x * 256 + threadIdx.x;   // < 69632
  int layer = idx >= 34816;
  int e = idx - layer * 34816;
  const float* inw = layer ? inw2 : inw1;
  const float* xpw = layer ? xpw2 : xpw1;
  const float* ow = layer ? ow2 : ow1;
  const float* pw = layer ? pw2 : pw1;
  float v;
  if (e < 16384) v = inw[e];
  else if (e < 22528) { int t = e - 16384; int r = t >> 7, c = t & 127; v = (r < 36) ? xpw[r * 128 + c] : 0.f; }
  else if (e < 30720) v = ow[e - 22528];
  else v = pw[e - 30720];
  wb[idx] = f2b(v);
}

// ---------------- instance-norm moments per (b,c) ----------------
__global__ __launch_bounds__(256) void k_stats(const float* __restrict__ p,
                                               float* __restrict__ stats) {
  int bc = blockIdx.x;
  const float* row = p + (size_t)bc * LL;
  float s = 0.f, s2 = 0.f;
  for (int i = threadIdx.x; i < LL; i += 256) {
    float v = row[i];
    s += v; s2 += v * v;
  }
  #pragma unroll
  for (int o = 32; o > 0; o >>= 1) {
    s += __shfl_down(s, o);
    s2 += __shfl_down(s2, o);
  }
  __shared__ float red[8];
  int w = threadIdx.x >> 6;
  if ((threadIdx.x & 63) == 0) { red[w] = s; red[4 + w] = s2; }
  __syncthreads();
  if (threadIdx.x == 0) {
    float S = red[0] + red[1] + red[2] + red[3];
    float S2 = red[4] + red[5] + red[6] + red[7];
    float m = S * (1.f / LL);
    float var = S2 * (1.f / LL) - m * m;
    stats[bc * 2] = m;
    stats[bc * 2 + 1] = rsqrtf(var + 1e-5f);
  }
}

// ------- transpose [b][c][l] -> [b][l][c], IN+relu, LayerNorm; xf fp32, xn bf16 -------
__global__ __launch_bounds__(256) void k_transln(const float* __restrict__ p,
                                                 const float* __restrict__ stats,
                                                 const float* __restrict__ g,
                                                 const float* __restrict__ be,
                                                 float* __restrict__ xf,
                                                 unsigned short* __restrict__ xn_b) {
  int b = blockIdx.x / NT;
  int l0 = (blockIdx.x % NT) * 64;
  __shared__ float T[64][65];
  int li = threadIdx.x & 63;
  int c0 = threadIdx.x >> 6;
  #pragma unroll
  for (int j = 0; j < 16; ++j) {
    int c = c0 * 16 + j;
    float m = stats[(b * CC + c) * 2];
    float rs = stats[(b * CC + c) * 2 + 1];
    float v = p[((size_t)(b * CC + c)) * LL + l0 + li];
    T[li][c] = fmaxf((v - m) * rs, 0.f);
  }
  __syncthreads();
  int lane = threadIdx.x & 63;
  int w = threadIdx.x >> 6;
  float gv = g[lane], bv = be[lane];
  for (int j = 0; j < 16; ++j) {
    int row = w * 16 + j;
    float v = T[row][lane];
    float s = v, s2 = v * v;
    #pragma unroll
    for (int o = 32; o > 0; o >>= 1) { s += __shfl_xor(s, o); s2 += __shfl_xor(s2, o); }
    float m = s * (1.f / 64.f);
    float var = s2 * (1.f / 64.f) - m * m;
    float rs = rsqrtf(var + 1e-5f);
    size_t off = ((size_t)b * LL + l0 + row) * CC + lane;
    xf[off] = v;
    xn_b[off] = f2b((v - m) * rs * gv + bv);
  }
}

// ---------------- in-proj MFMA: [36864x256] = xn[36864x64] @ in_w^T ----------------
__global__ __launch_bounds__(256) void k_inproj(const unsigned short* __restrict__ xn_b,
                                                const unsigned short* __restrict__ w_b,
                                                unsigned short* __restrict__ xin_b,
                                                unsigned short* __restrict__ z_b) {
  int wv = threadIdx.x >> 6, lane = threadIdx.x & 63;
  int m0 = blockIdx.x * 64 + wv * 16;
  int lr = lane & 15, kg = lane >> 4;
  bf16x8 a0 = *(const bf16x8*)&xn_b[(size_t)(m0 + lr) * CC + kg * 8];
  bf16x8 a1 = *(const bf16x8*)&xn_b[(size_t)(m0 + lr) * CC + 32 + kg * 8];
  fx4 acc[16];
  #pragma unroll
  for (int nt = 0; nt < 16; ++nt) {
    bf16x8 b0 = *(const bf16x8*)&w_b[(size_t)(nt * 16 + lr) * CC + kg * 8];
    bf16x8 b1 = *(const bf16x8*)&w_b[(size_t)(nt * 16 + lr) * CC + 32 + kg * 8];
    fx4 c = {0.f, 0.f, 0.f, 0.f};
    c = MFMA16(a0, b0, c, 0, 0, 0);
    c = MFMA16(a1, b1, c, 0, 0, 0);
    acc[nt] = c;
  }
  #pragma unroll
  for (int nt = 0; nt < 16; ++nt) {
    #pragma unroll
    for (int r = 0; r < 4; ++r) {
      int row = m0 + kg * 4 + r, col = nt * 16 + lr;
      unsigned short val = f2b(acc[nt][r]);
      if (col < 128) xin_b[(size_t)row * DI + col] = val;
      else           z_b[(size_t)row * DI + col - 128] = val;
    }
  }
}

// ---------------- depthwise causal conv (K=4) + SiLU; out fp32 + bf16 ----------------
__global__ __launch_bounds__(256) void k_conv(const unsigned short* __restrict__ xin_b,
                                              const float* __restrict__ cw,
                                              const float* __restrict__ cb,
                                              float* __restrict__ xc,
                                              unsigned short* __restrict__ xcb) {
  int idx = blockIdx.x * 256 + threadIdx.x;
  int d = idx & (DI - 1);
  int row = idx >> 7;
  int l = row % LL;
  float acc = cb[d];
  #pragma unroll
  for (int k = 0; k < 4; ++k) {
    int lk = l - 3 + k;
    if (lk >= 0) acc += b2f(xin_b[(size_t)(row - 3 + k) * DI + d]) * cw[d * 4 + k];
  }
  float s = acc / (1.f + __expf(-acc));
  xc[idx] = s;
  xcb[idx] = f2b(s);
}

// ---------------- x-proj MFMA: dbl[36864x36] = xc[36864x128] @ xp_w^T (N pad 48) ----------------
__global__ __launch_bounds__(256) void k_xp(const unsigned short* __restrict__ xcb,
                                            const unsigned short* __restrict__ w_b,
                                            float* __restrict__ dbl) {
  int wv = threadIdx.x >> 6, lane = threadIdx.x & 63;
  int m0 = blockIdx.x * 64 + wv * 16;
  int lr = lane & 15, kg = lane >> 4;
  fx4 acc[3];
  #pragma unroll
  for (int nt = 0; nt < 3; ++nt) acc[nt] = (fx4){0.f, 0.f, 0.f, 0.f};
  #pragma unroll
  for (int ks = 0; ks < 4; ++ks) {
    bf16x8 a = *(const bf16x8*)&xcb[(size_t)(m0 + lr) * DI + ks * 32 + kg * 8];
    #pragma unroll
    for (int nt = 0; nt < 3; ++nt) {
      bf16x8 b = *(const bf16x8*)&w_b[(size_t)(nt * 16 + lr) * DI + ks * 32 + kg * 8];
      acc[nt] = MFMA16(a, b, acc[nt], 0, 0, 0);
    }
  }
  #pragma unroll
  for (int nt = 0; nt < 3; ++nt) {
    #pragma unroll
    for (int r = 0; r < 4; ++r) {
      int row = m0 + kg * 4 + r, col = nt * 16 + lr;
      if (col < 36) dbl[(size_t)row * 36 + col] = acc[nt][r];
    }
  }
}

// dt on the fly: v = dt_b[d] + dot4(dbl[row][0..3], dt_w[d]); softplus
static __device__ __forceinline__ float softplus_f(float v) {
  return fmaxf(v, 0.f) + __logf(1.f + __expf(-fabsf(v)));
}

// ---------------- scan phase 1: per-chunk local scan ----------------
__global__ __launch_bounds__(128) void k_scanA(const float* __restrict__ dbl,
                                               const float* __restrict__ xc,
                                               const float* __restrict__ Alog,
                                               const float* __restrict__ dtw,
                                               const float* __restrict__ dtbp,
                                               float* __restrict__ ap,
                                               float* __restrict__ hl) {
  int g = blockIdx.x % GCH;
  int b = blockIdx.x / GCH;
  int d = threadIdx.x;
  float A[16];
  #pragma unroll
  for (int j = 0; j < 4; ++j) {
    float4 al = *(const float4*)&Alog[d * NS + j * 4];
    A[j * 4 + 0] = -__expf(al.x); A[j * 4 + 1] = -__expf(al.y);
    A[j * 4 + 2] = -__expf(al.z); A[j * 4 + 3] = -__expf(al.w);
  }
  float4 w4 = *(const float4*)&dtw[d * 4];
  float dtbv = dtbp[d];
  __shared__ float Bms[LCH * NS];
  __shared__ float Dts[LCH][4];
  {
    int idx = threadIdx.x * 4;
    int l = idx >> 4, n = idx & 15;
    *(float4*)&Bms[idx] = *(const float4*)&dbl[((size_t)b * LL + g * LCH + l) * 36 + 4 + n];
    if (threadIdx.x < 32)
      *(float4*)&Dts[threadIdx.x][0] = *(const float4*)&dbl[((size_t)b * LL + g * LCH + threadIdx.x) * 36];
  }
  __syncthreads();
  float h[16];
  #pragma unroll
  for (int n = 0; n < 16; ++n) h[n] = 0.f;
  float dtsum = 0.f;
  const float* xcp = xc + ((size_t)b * LL + g * LCH) * DI + d;
  #pragma unroll 4
  for (int l = 0; l < LCH; ++l) {
    float xcv = xcp[(size_t)l * DI];
    float4 q = *(float4*)&Dts[l][0];
    float v = dtbv + q.x * w4.x + q.y * w4.y + q.z * w4.z + q.w * w4.w;
    float dtv = softplus_f(v);
    float dx = dtv * xcv;
    dtsum += dtv;
    float4 b0 = *(float4*)&Bms[l * 16];
    float4 b1 = *(float4*)&Bms[l * 16 + 4];
    float4 b2 = *(float4*)&Bms[l * 16 + 8];
    float4 b3 = *(float4*)&Bms[l * 16 + 12];
    float a[16];
    #pragma unroll
    for (int n = 0; n < 16; ++n) a[n] = __expf(dtv * A[n]);
    h[0]  = a[0]  * h[0]  + dx * b0.x;  h[1]  = a[1]  * h[1]  + dx * b0.y;
    h[2]  = a[2]  * h[2]  + dx * b0.z;  h[3]  = a[3]  * h[3]  + dx * b0.w;
    h[4]  = a[4]  * h[4]  + dx * b1.x;  h[5]  = a[5]  * h[5]  + dx * b1.y;
    h[6]  = a[6]  * h[6]  + dx * b1.z;  h[7]  = a[7]  * h[7]  + dx * b1.w;
    h[8]  = a[8]  * h[8]  + dx * b2.x;  h[9]  = a[9]  * h[9]  + dx * b2.y;
    h[10] = a[10] * h[10] + dx * b2.z;  h[11] = a[11] * h[11] + dx * b2.w;
    h[12] = a[12] * h[12] + dx * b3.x;  h[13] = a[13] * h[13] + dx * b3.y;
    h[14] = a[14] * h[14] + dx * b3.z;  h[15] = a[15] * h[15] + dx * b3.w;
  }
  size_t o = (size_t)g * NSEQ + ((size_t)b * DI + d) * NS;
  #pragma unroll
  for (int j = 0; j < 4; ++j) {
    float4 av = make_float4(__expf(dtsum * A[j*4]), __expf(dtsum * A[j*4+1]),
                            __expf(dtsum * A[j*4+2]), __expf(dtsum * A[j*4+3]));
    *(float4*)&ap[o + j * 4] = av;
    *(float4*)&hl[o + j * 4] = make_float4(h[j*4], h[j*4+1], h[j*4+2], h[j*4+3]);
  }
}

// ---------------- scan phase 2a/2b/2c ----------------
__global__ __launch_bounds__(256) void k_scan2a(const float* __restrict__ ap,
                                                const float* __restrict__ hl,
                                                float* __restrict__ gap,
                                                float* __restrict__ ghl) {
  int t = blockIdx.x * 256 + threadIdx.x;
  int grp = t >> 13, seq = t & (NSEQ - 1);
  float A = 1.f, H = 0.f;
  int c0 = grp * GS;
  #pragma unroll 4
  for (int c = 0; c < GS; ++c) {
    float a = ap[(size_t)(c0 + c) * NSEQ + seq];
    float h = hl[(size_t)(c0 + c) * NSEQ + seq];
    H = a * H + h;
    A = a * A;
  }
  gap[t] = A;
  ghl[t] = H;
}

__global__ __launch_bounds__(256) void k_scan2b(const float* __restrict__ gap,
                                                const float* __restrict__ ghl,
                                                float* __restrict__ hig) {
  int seq = blockIdx.x * 256 + threadIdx.x;
  float h = 0.f;
  #pragma unroll
  for (int grp = 0; grp < NG; ++grp) {
    hig[grp * NSEQ + seq] = h;
    h = gap[grp * NSEQ + seq] * h + ghl[grp * NSEQ + seq];
  }
}

__global__ __launch_bounds__(256) void k_scan2c(const float* ap,   // == hi
                                                const float* __restrict__ hl,
                                                const float* __restrict__ hig,
                                                float* hi) {
  int t = blockIdx.x * 256 + threadIdx.x;
  int grp = t >> 13, seq = t & (NSEQ - 1);
  float h = hig[t];
  int c0 = grp * GS;
  size_t idx = (size_t)c0 * NSEQ + seq;
  float a = ap[idx], bb = hl[idx];
  for (int c = 0; c < GS; ++c) {
    size_t nidx = idx + NSEQ;
    float an = 0.f, bn = 0.f;
    if (c + 1 < GS) { an = ap[nidx]; bn = hl[nidx]; }
    hi[idx] = h;
    h = a * h + bb;
    a = an; bb = bn; idx = nidx;
  }
}

// ------- scan phase 3: replay; einsum-over-N; +D*xc; *silu(z); write y bf16 -------
__global__ __launch_bounds__(128) void k_scanC(const float* __restrict__ dbl,
                                               const float* __restrict__ xc,
                                               const unsigned short* z_b,  // y_b aliases
                                               const float* __restrict__ Alog,
                                               const float* __restrict__ dtw,
                                               const float* __restrict__ dtbp,
                                               const float* __restrict__ Dp,
                                               const float* __restrict__ hi,
                                               unsigned short* y_b) {
  int g = blockIdx.x % GCH;
  int b = blockIdx.x / GCH;
  int d = threadIdx.x;
  float A[16];
  #pragma unroll
  for (int j = 0; j < 4; ++j) {
    float4 al = *(const float4*)&Alog[d * NS + j * 4];
    A[j * 4 + 0] = -__expf(al.x); A[j * 4 + 1] = -__expf(al.y);
    A[j * 4 + 2] = -__expf(al.z); A[j * 4 + 3] = -__expf(al.w);
  }
  float4 w4 = *(const float4*)&dtw[d * 4];
  float dtbv = dtbp[d];
  float Dv = Dp[d];
  __shared__ float Bms[LCH * NS];
  __shared__ float Cms[LCH * NS];
  __shared__ float Dts[LCH][4];
  {
    int idx = threadIdx.x * 4;
    int l = idx >> 4, n = idx & 15;
    size_t rb = ((size_t)b * LL + g * LCH + l) * 36;
    *(float4*)&Bms[idx] = *(const float4*)&dbl[rb + 4 + n];
    *(float4*)&Cms[idx] = *(const float4*)&dbl[rb + 20 + n];
    if (threadIdx.x < 32)
      *(float4*)&Dts[threadIdx.x][0] = *(const float4*)&dbl[((size_t)b * LL + g * LCH + threadIdx.x) * 36];
  }
  __syncthreads();
  size_t o = (size_t)g * NSEQ + ((size_t)b * DI + d) * NS;
  float h[16];
  #pragma unroll
  for (int j = 0; j < 4; ++j) {
    float4 hv = *(const float4*)&hi[o + j * 4];
    h[j * 4 + 0] = hv.x; h[j * 4 + 1] = hv.y; h[j * 4 + 2] = hv.z; h[j * 4 + 3] = hv.w;
  }
  size_t base = ((size_t)b * LL + g * LCH) * DI + d;
  #pragma unroll 4
  for (int l = 0; l < LCH; ++l) {
    float xcv = xc[base + (size_t)l * DI];
    float zv = b2f(z_b[base + (size_t)l * DI]);
    float4 q = *(float4*)&Dts[l][0];
    float v = dtbv + q.x * w4.x + q.y * w4.y + q.z * w4.z + q.w * w4.w;
    float dtv = softplus_f(v);
    float4 b0 = *(float4*)&Bms[l * 16];
    float4 b1 = *(float4*)&Bms[l * 16 + 4];
    float4 b2 = *(float4*)&Bms[l * 16 + 8];
    float4 b3 = *(float4*)&Bms[l * 16 + 12];
    float4 c0 = *(float4*)&Cms[l * 16];
    float4 c1 = *(float4*)&Cms[l * 16 + 4];
    float4 c2 = *(float4*)&Cms[l * 16 + 8];
    float4 c3 = *(float4*)&Cms[l * 16 + 12];
    float a[16];
    #pragma unroll
    for (int n = 0; n < 16; ++n) a[n] = __expf(dtv * A[n]);
    float dx = dtv * xcv;
    float yv = Dv * xcv;
    h[0]  = a[0]  * h[0]  + dx * b0.x;  yv += h[0]  * c0.x;
    h[1]  = a[1]  * h[1]  + dx * b0.y;  yv += h[1]  * c0.y;
    h[2]  = a[2]  * h[2]  + dx * b0.z;  yv += h[2]  * c0.z;
    h[3]  = a[3]  * h[3]  + dx * b0.w;  yv += h[3]  * c0.w;
    h[4]  = a[4]  * h[4]  + dx * b1.x;  yv += h[4]  * c1.x;
    h[5]  = a[5]  * h[5]  + dx * b1.y;  yv += h[5]  * c1.y;
    h[6]  = a[6]  * h[6]  + dx * b1.z;  yv += h[6]  * c1.z;
    h[7]  = a[7]  * h[7]  + dx * b1.w;  yv += h[7]  * c1.w;
    h[8]  = a[8]  * h[8]  + dx * b2.x;  yv += h[8]  * c2.x;
    h[9]  = a[9]  * h[9]  + dx * b2.y;  yv += h[9]  * c2.y;
    h[10] = a[10] * h[10] + dx * b2.z;  yv += h[10] * c2.z;
    h[11] = a[11] * h[11] + dx * b2.w;  yv += h[11] * c2.w;
    h[12] = a[12] * h[12] + dx * b3.x;  yv += h[12] * c3.x;
    h[13] = a[13] * h[13] + dx * b3.y;  yv += h[13] * c3.y;
    h[14] = a[14] * h[14] + dx * b3.z;  yv += h[14] * c3.z;
    h[15] = a[15] * h[15] + dx * b3.w;  yv += h[15] * c3.w;
    float sg = zv / (1.f + __expf(-zv));
    y_b[base + (size_t)l * DI] = f2b(yv * sg);
  }
}

// ---------------- out-proj MFMA (K=128,N=64) + skip*xf -> tmp bf16 ----------------
__global__ __launch_bounds__(256) void k_outproj(const unsigned short* __restrict__ y_b,
                                                 const unsigned short* __restrict__ w_b,
                                                 const float* __restrict__ xf,
                                                 const float* __restrict__ skipv,
                                                 unsigned short* __restrict__ tmp_b) {
  int wv = threadIdx.x >> 6, lane = threadIdx.x & 63;
  int m0 = blockIdx.x * 64 + wv * 16;
  int lr = lane & 15, kg = lane >> 4;
  fx4 acc[4];
  #pragma unroll
  for (int nt = 0; nt < 4; ++nt) acc[nt] = (fx4){0.f, 0.f, 0.f, 0.f};
  #pragma unroll
  for (int ks = 0; ks < 4; ++ks) {
    bf16x8 a = *(const bf16x8*)&y_b[(size_t)(m0 + lr) * DI + ks * 32 + kg * 8];
    #pragma unroll
    for (int nt = 0; nt < 4; ++nt) {
      bf16x8 b = *(const bf16x8*)&w_b[(size_t)(nt * 16 + lr) * DI + ks * 32 + kg * 8];
      acc[nt] = MFMA16(a, b, acc[nt], 0, 0, 0);
    }
  }
  float sk = skipv[0];
  #pragma unroll
  for (int nt = 0; nt < 4; ++nt) {
    #pragma unroll
    for (int r = 0; r < 4; ++r) {
      int row = m0 + kg * 4 + r, col = nt * 16 + lr;
      float val = acc[nt][r] + sk * xf[(size_t)row * CC + col];
      tmp_b[(size_t)row * CC + col] = f2b(val);
    }
  }
}

// ---------------- pr-proj MFMA (c-major out) + pb (+identity), planar write ----------------
__global__ __launch_bounds__(256) void k_prproj(const unsigned short* __restrict__ tmp_b,
                                                const unsigned short* __restrict__ w_b,
                                                const float* __restrict__ pb,
                                                const float* __restrict__ ident,
                                                float* __restrict__ dst, int addid) {
  int wv = threadIdx.x >> 6, lane = threadIdx.x & 63;
  int m0 = blockIdx.x * 64 + wv * 16;   // global row (b*LL + l)
  int lr = lane & 15, kg = lane >> 4;
  int b = m0 / LL;
  int l0m = m0 - b * LL;
  fx4 acc[4];
  #pragma unroll
  for (int ct = 0; ct < 4; ++ct) acc[ct] = (fx4){0.f, 0.f, 0.f, 0.f};
  #pragma unroll
  for (int ks = 0; ks < 2; ++ks) {
    bf16x8 bfrag = *(const bf16x8*)&tmp_b[(size_t)(m0 + lr) * CC + ks * 32 + kg * 8];
    #pragma unroll
    for (int ct = 0; ct < 4; ++ct) {
      bf16x8 a = *(const bf16x8*)&w_b[(size_t)(ct * 16 + lr) * CC + ks * 32 + kg * 8];
      acc[ct] = MFMA16(a, bfrag, acc[ct], 0, 0, 0);
    }
  }
  #pragma unroll
  for (int ct = 0; ct < 4; ++ct) {
    #pragma unroll
    for (int r = 0; r < 4; ++r) {
      int c = ct * 16 + kg * 4 + r;
      int lpos = l0m + lr;
      size_t off = ((size_t)(b * CC + c)) * LL + lpos;
      float val = acc[ct][r] + pb[c];
      if (addid) val += ident[off];
      dst[off] = val;
    }
  }
}

extern "C" void kernel_launch(void* const* d_in, const int* in_sizes, int n_in,
                              void* d_out, int out_size, void* d_ws, size_t ws_size,
                              hipStream_t stream) {
  const float* x = (const float*)d_in[0];
  float* ws = (float*)d_ws;
  float* stats = ws;                                                  //     1024
  float* xf    = ws + 1024;                                           //  2359296
  unsigned short* xn_b = (unsigned short*)(ws + 2360320);             //  2359296 elems (1179648 w)
  unsigned short* z_b  = (unsigned short*)(ws + 3539968);             //  4718592 elems (2359296 w)
  float* xc    = ws + 5899264;                                        //  4718592 w
  unsigned short* xcb  = (unsigned short*)(ws + 10617856);            //  4718592 elems (2359296 w)
  unsigned short* xin_b = (unsigned short*)(ws + 12977152);           //  4718592 elems (2359296 w)
  float* dbl   = (float*)(ws + 12977152);                             //  alias xin_b (1327104 w)
  float* ap    = ws + 15336448;                                       //  2359296 w  (ap -> hi in-place)
  float* hl    = ws + 17695744;                                       //  2359296 w
  float* gap   = ws + 20055040;                                       //    73728
  float* ghl   = gap + 73728;
  float* hig   = ghl + 73728;
  unsigned short* wb = (unsigned short*)(hig + 73728);                //  69632 elems
  unsigned short* y_b   = z_b;   // alias: per-element read-before-write inside scanC
  unsigned short* tmp_b = xn_b;  // alias: xn dead after inproj
  float* inter = xc;             // alias: xc dead after scanC; consumed by next layer's transln
  float* outp  = (float*)d_out;

  k_cvt<<<272, 256, 0, stream>>>((const float*)d_in[3], (const float*)d_in[6],
                                 (const float*)d_in[11], (const float*)d_in[13],
                                 (const float*)d_in[17], (const float*)d_in[20],
                                 (const float*)d_in[25], (const float*)d_in[27], wb);

  const float* cur = x;
  for (int layer = 0; layer < 2; ++layer) {
    const int p0 = 1 + 14 * layer;
    const float* ln_g   = (const float*)d_in[p0 + 0];
    const float* ln_b   = (const float*)d_in[p0 + 1];
    const float* conv_w = (const float*)d_in[p0 + 3];
    const float* conv_b = (const float*)d_in[p0 + 4];
    const float* dt_w   = (const float*)d_in[p0 + 6];
    const float* dt_b   = (const float*)d_in[p0 + 7];
    const float* A_log  = (const float*)d_in[p0 + 8];
    const float* Dp     = (const float*)d_in[p0 + 9];
    const float* skip   = (const float*)d_in[p0 + 11];
    const float* pr_b   = (const float*)d_in[p0 + 13];
    const unsigned short* inw_b = wb + (size_t)layer * 34816;
    const unsigned short* xpw_b = inw_b + 16384;
    const unsigned short* ow_b  = inw_b + 22528;
    const unsigned short* pw_b  = inw_b + 30720;
    float* dst = (layer == 0) ? inter : outp;

    k_stats  <<<BB * CC, 256, 0, stream>>>(cur, stats);
    k_transln<<<BB * NT, 256, 0, stream>>>(cur, stats, ln_g, ln_b, xf, xn_b);
    k_inproj <<<(BB * LL) / 64, 256, 0, stream>>>(xn_b, inw_b, xin_b, z_b);
    k_conv   <<<(BB * LL * DI) / 256, 256, 0, stream>>>(xin_b, conv_w, conv_b, xc, xcb);
    k_xp     <<<(BB * LL) / 64, 256, 0, stream>>>(xcb, xpw_b, dbl);
    k_scanA  <<<BB * GCH, 128, 0, stream>>>(dbl, xc, A_log, dt_w, dt_b, ap, hl);
    k_scan2a <<<(NG * NSEQ) / 256, 256, 0, stream>>>(ap, hl, gap, ghl);
    k_scan2b <<<NSEQ / 256, 256, 0, stream>>>(gap, ghl, hig);
    k_scan2c <<<(NG * NSEQ) / 256, 256, 0, stream>>>(ap, hl, hig, ap /*hi*/);
    k_scanC  <<<BB * GCH, 128, 0, stream>>>(dbl, xc, z_b, A_log, dt_w, dt_b, Dp,
                                            ap /*hi*/, y_b);
    k_outproj<<<(BB * LL) / 64, 256, 0, stream>>>(y_b, ow_b, xf, skip, tmp_b);
    k_prproj <<<BB * NT, 256, 0, stream>>>(tmp_b, pw_b, pr_b, x, dst, layer);
    cur = inter;
  }
}

// Round 4
// 306.138 us; speedup vs baseline: 1.8104x; 1.0918x over previous
//
#include <hip/hip_runtime.h>
#include <math.h>

#define BB 4
#define CC 64
#define DI 128
#define NS 16
#define LL 9216
#define NT (LL / 64)

// scan decomposition
#define GCH 288
#define LCH 32
#define NSEQ 8192      // B*DI*NS
#define NG 9
#define GS 32

typedef __attribute__((ext_vector_type(8))) short bf16x8;
typedef __attribute__((ext_vector_type(4))) float fx4;
#define MFMA16 __builtin_amdgcn_mfma_f32_16x16x32_bf16

static __device__ __forceinline__ unsigned short f2b(float f) {
  unsigned u = __float_as_uint(f);
  u += 0x7fffu + ((u >> 16) & 1u);
  return (unsigned short)(u >> 16);
}
static __device__ __forceinline__ float b2f(unsigned short s) {
  return __uint_as_float(((unsigned)s) << 16);
}
static __device__ __forceinline__ float silu_f(float x) {
  return x / (1.f + __expf(-x));
}
static __device__ __forceinline__ float softplus_f(float v) {
  return fmaxf(v, 0.f) + __logf(1.f + __expf(-fabsf(v)));
}

// ---------------- weight bf16 conversion (once) ----------------
// per-layer pack: in_w[16384] | xp_w padded [48][128]=6144 | out_w[8192] | pr_w[4096]
__global__ __launch_bounds__(256) void k_cvt(const float* __restrict__ inw1, const float* __restrict__ xpw1,
                                             const float* __restrict__ ow1, const float* __restrict__ pw1,
                                             const float* __restrict__ inw2, const float* __restrict__ xpw2,
                                             const float* __restrict__ ow2, const float* __restrict__ pw2,
                                             unsigned short* __restrict__ wb) {
  int idx = blockIdx.x * 256 + threadIdx.x;   // < 69632
  int layer = idx >= 34816;
  int e = idx - layer * 34816;
  const float* inw = layer ? inw2 : inw1;
  const float* xpw = layer ? xpw2 : xpw1;
  const float* ow = layer ? ow2 : ow1;
  const float* pw = layer ? pw2 : pw1;
  float v;
  if (e < 16384) v = inw[e];
  else if (e < 22528) { int t = e - 16384; int r = t >> 7, c = t & 127; v = (r < 36) ? xpw[r * 128 + c] : 0.f; }
  else if (e < 30720) v = ow[e - 22528];
  else v = pw[e - 30720];
  wb[idx] = f2b(v);
}

// ---------------- instance-norm moments per (b,c) ----------------
__global__ __launch_bounds__(256) void k_stats(const float* __restrict__ p,
                                               float* __restrict__ stats) {
  int bc = blockIdx.x;
  const float* row = p + (size_t)bc * LL;
  float s = 0.f, s2 = 0.f;
  for (int i = threadIdx.x; i < LL; i += 256) {
    float v = row[i];
    s += v; s2 += v * v;
  }
  #pragma unroll
  for (int o = 32; o > 0; o >>= 1) {
    s += __shfl_down(s, o);
    s2 += __shfl_down(s2, o);
  }
  __shared__ float red[8];
  int w = threadIdx.x >> 6;
  if ((threadIdx.x & 63) == 0) { red[w] = s; red[4 + w] = s2; }
  __syncthreads();
  if (threadIdx.x == 0) {
    float S = red[0] + red[1] + red[2] + red[3];
    float S2 = red[4] + red[5] + red[6] + red[7];
    float m = S * (1.f / LL);
    float var = S2 * (1.f / LL) - m * m;
    stats[bc * 2] = m;
    stats[bc * 2 + 1] = rsqrtf(var + 1e-5f);
  }
}

// ---- fused: transpose + IN + relu + LN + in-proj MFMA -> xf, xin_b, z_b ----
__global__ __launch_bounds__(256) void k_fusein(const float* __restrict__ p,
                                                const float* __restrict__ stats,
                                                const float* __restrict__ g,
                                                const float* __restrict__ be,
                                                const unsigned short* __restrict__ w_b,
                                                float* __restrict__ xf,
                                                unsigned short* __restrict__ xin_b,
                                                unsigned short* __restrict__ z_b) {
  int b = blockIdx.x / NT;
  int l0 = (blockIdx.x % NT) * 64;
  __shared__ float T[64][65];
  __shared__ unsigned short Tb[64][72];   // bf16 LN output, 16B-aligned rows
  int li = threadIdx.x & 63;
  int c0 = threadIdx.x >> 6;
  #pragma unroll
  for (int j = 0; j < 16; ++j) {
    int c = c0 * 16 + j;
    float m = stats[(b * CC + c) * 2];
    float rs = stats[(b * CC + c) * 2 + 1];
    float v = p[((size_t)(b * CC + c)) * LL + l0 + li];
    T[li][c] = fmaxf((v - m) * rs, 0.f);
  }
  __syncthreads();
  int lane = threadIdx.x & 63;
  int w = threadIdx.x >> 6;
  float gv = g[lane], bv = be[lane];
  for (int j = 0; j < 16; ++j) {
    int row = w * 16 + j;
    float v = T[row][lane];
    float s = v, s2 = v * v;
    #pragma unroll
    for (int o = 32; o > 0; o >>= 1) { s += __shfl_xor(s, o); s2 += __shfl_xor(s2, o); }
    float m = s * (1.f / 64.f);
    float var = s2 * (1.f / 64.f) - m * m;
    float rs = rsqrtf(var + 1e-5f);
    size_t off = ((size_t)b * LL + l0 + row) * CC + lane;
    xf[off] = v;
    Tb[row][lane] = f2b((v - m) * rs * gv + bv);
  }
  __syncthreads();
  // in-proj MFMA from LDS tile
  int wv = threadIdx.x >> 6;
  int lr = lane & 15, kg = lane >> 4;
  int m0 = wv * 16;
  int rowg0 = blockIdx.x * 64 + m0;       // == b*LL + l0 + m0
  bf16x8 a0 = *(const bf16x8*)&Tb[m0 + lr][kg * 8];
  bf16x8 a1 = *(const bf16x8*)&Tb[m0 + lr][32 + kg * 8];
  #pragma unroll
  for (int nt = 0; nt < 16; ++nt) {
    bf16x8 b0 = *(const bf16x8*)&w_b[(size_t)(nt * 16 + lr) * CC + kg * 8];
    bf16x8 b1 = *(const bf16x8*)&w_b[(size_t)(nt * 16 + lr) * CC + 32 + kg * 8];
    fx4 c = {0.f, 0.f, 0.f, 0.f};
    c = MFMA16(a0, b0, c, 0, 0, 0);
    c = MFMA16(a1, b1, c, 0, 0, 0);
    #pragma unroll
    for (int r = 0; r < 4; ++r) {
      int row = rowg0 + kg * 4 + r, col = nt * 16 + lr;
      unsigned short val = f2b(c[r]);
      if (col < 128) xin_b[(size_t)row * DI + col] = val;
      else           z_b[(size_t)row * DI + col - 128] = val;
    }
  }
}

// ---- x-proj MFMA with conv+silu on the fly: dbl[36864x36] = xc @ xp_w^T ----
__global__ __launch_bounds__(256) void k_xp(const unsigned short* __restrict__ xin_b,
                                            const float* __restrict__ cw,
                                            const float* __restrict__ cb,
                                            const unsigned short* __restrict__ w_b,
                                            float* __restrict__ dbl) {
  int wv = threadIdx.x >> 6, lane = threadIdx.x & 63;
  int m0 = blockIdx.x * 64 + wv * 16;
  int lr = lane & 15, kg = lane >> 4;
  int row = m0 + lr;
  int l = row % LL;
  const bf16x8 zv = {0, 0, 0, 0, 0, 0, 0, 0};
  fx4 acc[3];
  #pragma unroll
  for (int nt = 0; nt < 3; ++nt) acc[nt] = (fx4){0.f, 0.f, 0.f, 0.f};
  #pragma unroll
  for (int ks = 0; ks < 4; ++ks) {
    int cbase = ks * 32 + kg * 8;
    bf16x8 x3 = *(const bf16x8*)&xin_b[(size_t)row * DI + cbase];
    bf16x8 x2 = (l >= 1) ? *(const bf16x8*)&xin_b[(size_t)(row - 1) * DI + cbase] : zv;
    bf16x8 x1 = (l >= 2) ? *(const bf16x8*)&xin_b[(size_t)(row - 2) * DI + cbase] : zv;
    bf16x8 x0 = (l >= 3) ? *(const bf16x8*)&xin_b[(size_t)(row - 3) * DI + cbase] : zv;
    bf16x8 a;
    #pragma unroll
    for (int e = 0; e < 8; ++e) {
      int d = cbase + e;
      float4 w4 = *(const float4*)&cw[d * 4];
      float v = cb[d] + b2f((unsigned short)x0[e]) * w4.x + b2f((unsigned short)x1[e]) * w4.y
              + b2f((unsigned short)x2[e]) * w4.z + b2f((unsigned short)x3[e]) * w4.w;
      a[e] = (short)f2b(silu_f(v));
    }
    #pragma unroll
    for (int nt = 0; nt < 3; ++nt) {
      bf16x8 bfr = *(const bf16x8*)&w_b[(size_t)(nt * 16 + lr) * DI + cbase];
      acc[nt] = MFMA16(a, bfr, acc[nt], 0, 0, 0);
    }
  }
  #pragma unroll
  for (int nt = 0; nt < 3; ++nt) {
    #pragma unroll
    for (int r = 0; r < 4; ++r) {
      int orow = m0 + kg * 4 + r, col = nt * 16 + lr;
      if (col < 36) dbl[(size_t)orow * 36 + col] = acc[nt][r];
    }
  }
}

// ---------------- scan phase 1: local scan; conv+silu via sliding window ----------------
__global__ __launch_bounds__(128) void k_scanA(const float* __restrict__ dbl,
                                               const unsigned short* __restrict__ xin_b,
                                               const float* __restrict__ cw,
                                               const float* __restrict__ cb,
                                               const float* __restrict__ Alog,
                                               const float* __restrict__ dtw,
                                               const float* __restrict__ dtbp,
                                               float* __restrict__ ap,
                                               float* __restrict__ hl) {
  int g = blockIdx.x % GCH;
  int b = blockIdx.x / GCH;
  int d = threadIdx.x;
  float A[16];
  #pragma unroll
  for (int j = 0; j < 4; ++j) {
    float4 al = *(const float4*)&Alog[d * NS + j * 4];
    A[j * 4 + 0] = -__expf(al.x); A[j * 4 + 1] = -__expf(al.y);
    A[j * 4 + 2] = -__expf(al.z); A[j * 4 + 3] = -__expf(al.w);
  }
  float4 w4 = *(const float4*)&dtw[d * 4];
  float dtbv = dtbp[d];
  float4 cw4 = *(const float4*)&cw[d * 4];
  float cbv = cb[d];
  __shared__ float Bms[LCH * NS];
  __shared__ float Dts[LCH][4];
  {
    int idx = threadIdx.x * 4;
    int l = idx >> 4, n = idx & 15;
    *(float4*)&Bms[idx] = *(const float4*)&dbl[((size_t)b * LL + g * LCH + l) * 36 + 4 + n];
    if (threadIdx.x < 32)
      *(float4*)&Dts[threadIdx.x][0] = *(const float4*)&dbl[((size_t)b * LL + g * LCH + threadIdx.x) * 36];
  }
  __syncthreads();
  const unsigned short* xip = xin_b + ((size_t)b * LL + g * LCH) * DI + d;
  float w0 = 0.f, w1 = 0.f, w2 = 0.f;
  if (g > 0) {
    w0 = b2f(xip[-3 * DI]); w1 = b2f(xip[-2 * DI]); w2 = b2f(xip[-DI]);
  }
  float h[16];
  #pragma unroll
  for (int n = 0; n < 16; ++n) h[n] = 0.f;
  float dtsum = 0.f;
  #pragma unroll 4
  for (int l = 0; l < LCH; ++l) {
    float xv = b2f(xip[(size_t)l * DI]);
    float cacc = cbv + w0 * cw4.x + w1 * cw4.y + w2 * cw4.z + xv * cw4.w;
    float xcv = silu_f(cacc);
    w0 = w1; w1 = w2; w2 = xv;
    float4 q = *(float4*)&Dts[l][0];
    float v = dtbv + q.x * w4.x + q.y * w4.y + q.z * w4.z + q.w * w4.w;
    float dtv = softplus_f(v);
    float dx = dtv * xcv;
    dtsum += dtv;
    float4 b0 = *(float4*)&Bms[l * 16];
    float4 b1 = *(float4*)&Bms[l * 16 + 4];
    float4 b2 = *(float4*)&Bms[l * 16 + 8];
    float4 b3 = *(float4*)&Bms[l * 16 + 12];
    float a[16];
    #pragma unroll
    for (int n = 0; n < 16; ++n) a[n] = __expf(dtv * A[n]);
    h[0]  = a[0]  * h[0]  + dx * b0.x;  h[1]  = a[1]  * h[1]  + dx * b0.y;
    h[2]  = a[2]  * h[2]  + dx * b0.z;  h[3]  = a[3]  * h[3]  + dx * b0.w;
    h[4]  = a[4]  * h[4]  + dx * b1.x;  h[5]  = a[5]  * h[5]  + dx * b1.y;
    h[6]  = a[6]  * h[6]  + dx * b1.z;  h[7]  = a[7]  * h[7]  + dx * b1.w;
    h[8]  = a[8]  * h[8]  + dx * b2.x;  h[9]  = a[9]  * h[9]  + dx * b2.y;
    h[10] = a[10] * h[10] + dx * b2.z;  h[11] = a[11] * h[11] + dx * b2.w;
    h[12] = a[12] * h[12] + dx * b3.x;  h[13] = a[13] * h[13] + dx * b3.y;
    h[14] = a[14] * h[14] + dx * b3.z;  h[15] = a[15] * h[15] + dx * b3.w;
  }
  size_t o = (size_t)g * NSEQ + ((size_t)b * DI + d) * NS;
  #pragma unroll
  for (int j = 0; j < 4; ++j) {
    float4 av = make_float4(__expf(dtsum * A[j*4]), __expf(dtsum * A[j*4+1]),
                            __expf(dtsum * A[j*4+2]), __expf(dtsum * A[j*4+3]));
    *(float4*)&ap[o + j * 4] = av;
    *(float4*)&hl[o + j * 4] = make_float4(h[j*4], h[j*4+1], h[j*4+2], h[j*4+3]);
  }
}

// ---------------- scan phase 2a/2b/2c ----------------
__global__ __launch_bounds__(256) void k_scan2a(const float* __restrict__ ap,
                                                const float* __restrict__ hl,
                                                float* __restrict__ gap,
                                                float* __restrict__ ghl) {
  int t = blockIdx.x * 256 + threadIdx.x;
  int grp = t >> 13, seq = t & (NSEQ - 1);
  float A = 1.f, H = 0.f;
  int c0 = grp * GS;
  #pragma unroll 4
  for (int c = 0; c < GS; ++c) {
    float a = ap[(size_t)(c0 + c) * NSEQ + seq];
    float h = hl[(size_t)(c0 + c) * NSEQ + seq];
    H = a * H + h;
    A = a * A;
  }
  gap[t] = A;
  ghl[t] = H;
}

__global__ __launch_bounds__(256) void k_scan2b(const float* __restrict__ gap,
                                                const float* __restrict__ ghl,
                                                float* __restrict__ hig) {
  int seq = blockIdx.x * 256 + threadIdx.x;
  float h = 0.f;
  #pragma unroll
  for (int grp = 0; grp < NG; ++grp) {
    hig[grp * NSEQ + seq] = h;
    h = gap[grp * NSEQ + seq] * h + ghl[grp * NSEQ + seq];
  }
}

__global__ __launch_bounds__(256) void k_scan2c(const float* ap,   // == hi
                                                const float* __restrict__ hl,
                                                const float* __restrict__ hig,
                                                float* hi) {
  int t = blockIdx.x * 256 + threadIdx.x;
  int grp = t >> 13, seq = t & (NSEQ - 1);
  float h = hig[t];
  int c0 = grp * GS;
  size_t idx = (size_t)c0 * NSEQ + seq;
  float a = ap[idx], bb = hl[idx];
  for (int c = 0; c < GS; ++c) {
    size_t nidx = idx + NSEQ;
    float an = 0.f, bn = 0.f;
    if (c + 1 < GS) { an = ap[nidx]; bn = hl[nidx]; }
    hi[idx] = h;
    h = a * h + bb;
    a = an; bb = bn; idx = nidx;
  }
}

// ------- scan phase 3: replay; conv window; einsum; +D*xc; *silu(z); y bf16 -------
__global__ __launch_bounds__(128) void k_scanC(const float* __restrict__ dbl,
                                               const unsigned short* __restrict__ xin_b,
                                               const float* __restrict__ cw,
                                               const float* __restrict__ cb,
                                               const unsigned short* z_b,  // y_b aliases
                                               const float* __restrict__ Alog,
                                               const float* __restrict__ dtw,
                                               const float* __restrict__ dtbp,
                                               const float* __restrict__ Dp,
                                               const float* __restrict__ hi,
                                               unsigned short* y_b) {
  int g = blockIdx.x % GCH;
  int b = blockIdx.x / GCH;
  int d = threadIdx.x;
  float A[16];
  #pragma unroll
  for (int j = 0; j < 4; ++j) {
    float4 al = *(const float4*)&Alog[d * NS + j * 4];
    A[j * 4 + 0] = -__expf(al.x); A[j * 4 + 1] = -__expf(al.y);
    A[j * 4 + 2] = -__expf(al.z); A[j * 4 + 3] = -__expf(al.w);
  }
  float4 w4 = *(const float4*)&dtw[d * 4];
  float dtbv = dtbp[d];
  float Dv = Dp[d];
  float4 cw4 = *(const float4*)&cw[d * 4];
  float cbv = cb[d];
  __shared__ float Bms[LCH * NS];
  __shared__ float Cms[LCH * NS];
  __shared__ float Dts[LCH][4];
  {
    int idx = threadIdx.x * 4;
    int l = idx >> 4, n = idx & 15;
    size_t rb = ((size_t)b * LL + g * LCH + l) * 36;
    *(float4*)&Bms[idx] = *(const float4*)&dbl[rb + 4 + n];
    *(float4*)&Cms[idx] = *(const float4*)&dbl[rb + 20 + n];
    if (threadIdx.x < 32)
      *(float4*)&Dts[threadIdx.x][0] = *(const float4*)&dbl[((size_t)b * LL + g * LCH + threadIdx.x) * 36];
  }
  __syncthreads();
  size_t o = (size_t)g * NSEQ + ((size_t)b * DI + d) * NS;
  float h[16];
  #pragma unroll
  for (int j = 0; j < 4; ++j) {
    float4 hv = *(const float4*)&hi[o + j * 4];
    h[j * 4 + 0] = hv.x; h[j * 4 + 1] = hv.y; h[j * 4 + 2] = hv.z; h[j * 4 + 3] = hv.w;
  }
  size_t base = ((size_t)b * LL + g * LCH) * DI + d;
  const unsigned short* xip = xin_b + base;
  float w0 = 0.f, w1 = 0.f, w2 = 0.f;
  if (g > 0) {
    w0 = b2f(xip[-3 * DI]); w1 = b2f(xip[-2 * DI]); w2 = b2f(xip[-DI]);
  }
  #pragma unroll 4
  for (int l = 0; l < LCH; ++l) {
    float xv = b2f(xip[(size_t)l * DI]);
    float cacc = cbv + w0 * cw4.x + w1 * cw4.y + w2 * cw4.z + xv * cw4.w;
    float xcv = silu_f(cacc);
    w0 = w1; w1 = w2; w2 = xv;
    float zv = b2f(z_b[base + (size_t)l * DI]);
    float4 q = *(float4*)&Dts[l][0];
    float v = dtbv + q.x * w4.x + q.y * w4.y + q.z * w4.z + q.w * w4.w;
    float dtv = softplus_f(v);
    float4 b0 = *(float4*)&Bms[l * 16];
    float4 b1 = *(float4*)&Bms[l * 16 + 4];
    float4 b2 = *(float4*)&Bms[l * 16 + 8];
    float4 b3 = *(float4*)&Bms[l * 16 + 12];
    float4 c0 = *(float4*)&Cms[l * 16];
    float4 c1 = *(float4*)&Cms[l * 16 + 4];
    float4 c2 = *(float4*)&Cms[l * 16 + 8];
    float4 c3 = *(float4*)&Cms[l * 16 + 12];
    float a[16];
    #pragma unroll
    for (int n = 0; n < 16; ++n) a[n] = __expf(dtv * A[n]);
    float dx = dtv * xcv;
    float yv = Dv * xcv;
    h[0]  = a[0]  * h[0]  + dx * b0.x;  yv += h[0]  * c0.x;
    h[1]  = a[1]  * h[1]  + dx * b0.y;  yv += h[1]  * c0.y;
    h[2]  = a[2]  * h[2]  + dx * b0.z;  yv += h[2]  * c0.z;
    h[3]  = a[3]  * h[3]  + dx * b0.w;  yv += h[3]  * c0.w;
    h[4]  = a[4]  * h[4]  + dx * b1.x;  yv += h[4]  * c1.x;
    h[5]  = a[5]  * h[5]  + dx * b1.y;  yv += h[5]  * c1.y;
    h[6]  = a[6]  * h[6]  + dx * b1.z;  yv += h[6]  * c1.z;
    h[7]  = a[7]  * h[7]  + dx * b1.w;  yv += h[7]  * c1.w;
    h[8]  = a[8]  * h[8]  + dx * b2.x;  yv += h[8]  * c2.x;
    h[9]  = a[9]  * h[9]  + dx * b2.y;  yv += h[9]  * c2.y;
    h[10] = a[10] * h[10] + dx * b2.z;  yv += h[10] * c2.z;
    h[11] = a[11] * h[11] + dx * b2.w;  yv += h[11] * c2.w;
    h[12] = a[12] * h[12] + dx * b3.x;  yv += h[12] * c3.x;
    h[13] = a[13] * h[13] + dx * b3.y;  yv += h[13] * c3.y;
    h[14] = a[14] * h[14] + dx * b3.z;  yv += h[14] * c3.z;
    h[15] = a[15] * h[15] + dx * b3.w;  yv += h[15] * c3.w;
    float sg = silu_f(zv);
    y_b[base + (size_t)l * DI] = f2b(yv * sg);
  }
}

// ---- fused epilogue: out-proj + skip*xf -> LDS bf16 tile -> pr-proj + pb (+ident) ----
__global__ __launch_bounds__(256) void k_outpr(const unsigned short* __restrict__ y_b,
                                               const unsigned short* __restrict__ ow_b,
                                               const float* __restrict__ xf,
                                               const float* __restrict__ skipv,
                                               const unsigned short* __restrict__ pw_b,
                                               const float* __restrict__ pb,
                                               const float* __restrict__ ident,
                                               float* __restrict__ dst, int addid) {
  int wv = threadIdx.x >> 6, lane = threadIdx.x & 63;
  int lr = lane & 15, kg = lane >> 4;
  int m0g = blockIdx.x * 64 + wv * 16;
  __shared__ unsigned short Tb[64][72];
  // phase 1: out-proj rows [m0g, m0g+16), cols 0..64 ; + skip*xf ; -> Tb
  fx4 acc[4];
  #pragma unroll
  for (int nt = 0; nt < 4; ++nt) acc[nt] = (fx4){0.f, 0.f, 0.f, 0.f};
  #pragma unroll
  for (int ks = 0; ks < 4; ++ks) {
    bf16x8 a = *(const bf16x8*)&y_b[(size_t)(m0g + lr) * DI + ks * 32 + kg * 8];
    #pragma unroll
    for (int nt = 0; nt < 4; ++nt) {
      bf16x8 bfr = *(const bf16x8*)&ow_b[(size_t)(nt * 16 + lr) * DI + ks * 32 + kg * 8];
      acc[nt] = MFMA16(a, bfr, acc[nt], 0, 0, 0);
    }
  }
  float sk = skipv[0];
  #pragma unroll
  for (int nt = 0; nt < 4; ++nt) {
    #pragma unroll
    for (int r = 0; r < 4; ++r) {
      int rowl = wv * 16 + kg * 4 + r, col = nt * 16 + lr;
      float val = acc[nt][r] + sk * xf[(size_t)(blockIdx.x * 64 + rowl) * CC + col];
      Tb[rowl][col] = f2b(val);
    }
  }
  __syncthreads();
  // phase 2: pr-proj; output [c][l] planar
  int b = (blockIdx.x * 64) / LL;
  int l0m = blockIdx.x * 64 - b * LL;
  fx4 pacc[4];
  #pragma unroll
  for (int ct = 0; ct < 4; ++ct) pacc[ct] = (fx4){0.f, 0.f, 0.f, 0.f};
  #pragma unroll
  for (int ks = 0; ks < 2; ++ks) {
    bf16x8 bfrag = *(const bf16x8*)&Tb[wv * 16 + lr][ks * 32 + kg * 8];
    #pragma unroll
    for (int ct = 0; ct < 4; ++ct) {
      bf16x8 a = *(const bf16x8*)&pw_b[(size_t)(ct * 16 + lr) * CC + ks * 32 + kg * 8];
      pacc[ct] = MFMA16(a, bfrag, pacc[ct], 0, 0, 0);
    }
  }
  #pragma unroll
  for (int ct = 0; ct < 4; ++ct) {
    #pragma unroll
    for (int r = 0; r < 4; ++r) {
      int c = ct * 16 + kg * 4 + r;
      int lpos = l0m + wv * 16 + lr;
      size_t off = ((size_t)(b * CC + c)) * LL + lpos;
      float val = pacc[ct][r] + pb[c];
      if (addid) val += ident[off];
      dst[off] = val;
    }
  }
}

extern "C" void kernel_launch(void* const* d_in, const int* in_sizes, int n_in,
                              void* d_out, int out_size, void* d_ws, size_t ws_size,
                              hipStream_t stream) {
  const float* x = (const float*)d_in[0];
  float* ws = (float*)d_ws;
  float* stats = ws;                                        //      1024
  float* xf    = ws + 1024;                                 //  2359296
  unsigned short* xin_b = (unsigned short*)(ws + 2360320);  //  2359296 words
  unsigned short* z_b   = (unsigned short*)(ws + 4719616);  //  2359296 words
  float* dbl   = ws + 7078912;                              //  1327104
  float* ap    = ws + 8406016;                              //  2359296 (ap -> hi in-place; inter aliases)
  float* hl    = ws + 10765312;                             //  2359296
  float* gap   = ws + 13124608;                             //    73728
  float* ghl   = gap + 73728;
  float* hig   = ghl + 73728;
  unsigned short* wb = (unsigned short*)(hig + 73728);      //  69632 elems
  unsigned short* y_b = z_b;   // alias: scanC reads z[e] then writes y[e]
  float* inter = ap;           // alias: ap/hi dead after scanC; outpr(L0) writes it,
                               //        L1 consumes it in stats/fusein before scanA clobbers
  float* outp  = (float*)d_out;

  k_cvt<<<272, 256, 0, stream>>>((const float*)d_in[3], (const float*)d_in[6],
                                 (const float*)d_in[11], (const float*)d_in[13],
                                 (const float*)d_in[17], (const float*)d_in[20],
                                 (const float*)d_in[25], (const float*)d_in[27], wb);

  const float* cur = x;
  for (int layer = 0; layer < 2; ++layer) {
    const int p0 = 1 + 14 * layer;
    const float* ln_g   = (const float*)d_in[p0 + 0];
    const float* ln_b   = (const float*)d_in[p0 + 1];
    const float* conv_w = (const float*)d_in[p0 + 3];
    const float* conv_b = (const float*)d_in[p0 + 4];
    const float* dt_w   = (const float*)d_in[p0 + 6];
    const float* dt_b   = (const float*)d_in[p0 + 7];
    const float* A_log  = (const float*)d_in[p0 + 8];
    const float* Dp     = (const float*)d_in[p0 + 9];
    const float* skip   = (const float*)d_in[p0 + 11];
    const float* pr_b   = (const float*)d_in[p0 + 13];
    const unsigned short* inw_b = wb + (size_t)layer * 34816;
    const unsigned short* xpw_b = inw_b + 16384;
    const unsigned short* ow_b  = inw_b + 22528;
    const unsigned short* pw_b  = inw_b + 30720;
    float* dst = (layer == 0) ? inter : outp;

    k_stats <<<BB * CC, 256, 0, stream>>>(cur, stats);
    k_fusein<<<BB * NT, 256, 0, stream>>>(cur, stats, ln_g, ln_b, inw_b, xf, xin_b, z_b);
    k_xp    <<<(BB * LL) / 64, 256, 0, stream>>>(xin_b, conv_w, conv_b, xpw_b, dbl);
    k_scanA <<<BB * GCH, 128, 0, stream>>>(dbl, xin_b, conv_w, conv_b, A_log, dt_w, dt_b, ap, hl);
    k_scan2a<<<(NG * NSEQ) / 256, 256, 0, stream>>>(ap, hl, gap, ghl);
    k_scan2b<<<NSEQ / 256, 256, 0, stream>>>(gap, ghl, hig);
    k_scan2c<<<(NG * NSEQ) / 256, 256, 0, stream>>>(ap, hl, hig, ap /*hi*/);
    k_scanC <<<BB * GCH, 128, 0, stream>>>(dbl, xin_b, conv_w, conv_b, z_b, A_log,
                                           dt_w, dt_b, Dp, ap /*hi*/, y_b);
    k_outpr <<<(BB * LL) / 64, 256, 0, stream>>>(y_b, ow_b, xf, skip, pw_b, pr_b,
                                                 x, dst, layer);
    cur = inter;
  }
}

// Round 6
// 294.714 us; speedup vs baseline: 1.8805x; 1.0388x over previous
//
#include <hip/hip_runtime.h>
#include <math.h>

#define BB 4
#define CC 64
#define DI 128
#define NS 16
#define LL 9216
#define NT (LL / 64)

// scan decomposition
#define GCH 288
#define LCH 32
#define NSEQ 8192      // B*DI*NS
#define NG 9
#define GS 32

typedef __attribute__((ext_vector_type(8))) short bf16x8;
typedef __attribute__((ext_vector_type(4))) float fx4;
#define MFMA16 __builtin_amdgcn_mfma_f32_16x16x32_bf16

static __device__ __forceinline__ unsigned short f2b(float f) {
  unsigned u = __float_as_uint(f);
  u += 0x7fffu + ((u >> 16) & 1u);
  return (unsigned short)(u >> 16);
}
static __device__ __forceinline__ float b2f(unsigned short s) {
  return __uint_as_float(((unsigned)s) << 16);
}
static __device__ __forceinline__ float silu_f(float x) {
  return x / (1.f + __expf(-x));
}
static __device__ __forceinline__ float softplus_f(float v) {
  return fmaxf(v, 0.f) + __logf(1.f + __expf(-fabsf(v)));
}

// ---------------- weight bf16 conversion (once) ----------------
// per-layer pack: in_w[16384] | xp_w padded [48][128]=6144 | out_w[8192] | pr_w[4096]
__global__ __launch_bounds__(256) void k_cvt(const float* __restrict__ inw1, const float* __restrict__ xpw1,
                                             const float* __restrict__ ow1, const float* __restrict__ pw1,
                                             const float* __restrict__ inw2, const float* __restrict__ xpw2,
                                             const float* __restrict__ ow2, const float* __restrict__ pw2,
                                             unsigned short* __restrict__ wb) {
  int idx = blockIdx.x * 256 + threadIdx.x;   // < 69632
  int layer = idx >= 34816;
  int e = idx - layer * 34816;
  const float* inw = layer ? inw2 : inw1;
  const float* xpw = layer ? xpw2 : xpw1;
  const float* ow = layer ? ow2 : ow1;
  const float* pw = layer ? pw2 : pw1;
  float v;
  if (e < 16384) v = inw[e];
  else if (e < 22528) { int t = e - 16384; int r = t >> 7, c = t & 127; v = (r < 36) ? xpw[r * 128 + c] : 0.f; }
  else if (e < 30720) v = ow[e - 22528];
  else v = pw[e - 30720];
  wb[idx] = f2b(v);
}

// ---------------- instance-norm moments per (b,c) ----------------
__global__ __launch_bounds__(256) void k_stats(const float* __restrict__ p,
                                               float* __restrict__ stats) {
  int bc = blockIdx.x;
  const float* row = p + (size_t)bc * LL;
  float s = 0.f, s2 = 0.f;
  for (int i = threadIdx.x; i < LL; i += 256) {
    float v = row[i];
    s += v; s2 += v * v;
  }
  #pragma unroll
  for (int o = 32; o > 0; o >>= 1) {
    s += __shfl_down(s, o);
    s2 += __shfl_down(s2, o);
  }
  __shared__ float red[8];
  int w = threadIdx.x >> 6;
  if ((threadIdx.x & 63) == 0) { red[w] = s; red[4 + w] = s2; }
  __syncthreads();
  if (threadIdx.x == 0) {
    float S = red[0] + red[1] + red[2] + red[3];
    float S2 = red[4] + red[5] + red[6] + red[7];
    float m = S * (1.f / LL);
    float var = S2 * (1.f / LL) - m * m;
    stats[bc * 2] = m;
    stats[bc * 2 + 1] = rsqrtf(var + 1e-5f);
  }
}

// ---- fused: transpose + IN + relu + LN + in-proj MFMA -> xf, xin_b, z_b ----
__global__ __launch_bounds__(256) void k_fusein(const float* __restrict__ p,
                                                const float* __restrict__ stats,
                                                const float* __restrict__ g,
                                                const float* __restrict__ be,
                                                const unsigned short* __restrict__ w_b,
                                                float* __restrict__ xf,
                                                unsigned short* __restrict__ xin_b,
                                                unsigned short* __restrict__ z_b) {
  int b = blockIdx.x / NT;
  int l0 = (blockIdx.x % NT) * 64;
  __shared__ float T[64][65];
  __shared__ unsigned short Tb[64][72];   // bf16 LN output, 16B-aligned rows
  int li = threadIdx.x & 63;
  int c0 = threadIdx.x >> 6;
  #pragma unroll
  for (int j = 0; j < 16; ++j) {
    int c = c0 * 16 + j;
    float m = stats[(b * CC + c) * 2];
    float rs = stats[(b * CC + c) * 2 + 1];
    float v = p[((size_t)(b * CC + c)) * LL + l0 + li];
    T[li][c] = fmaxf((v - m) * rs, 0.f);
  }
  __syncthreads();
  int lane = threadIdx.x & 63;
  int w = threadIdx.x >> 6;
  float gv = g[lane], bv = be[lane];
  for (int j = 0; j < 16; ++j) {
    int row = w * 16 + j;
    float v = T[row][lane];
    float s = v, s2 = v * v;
    #pragma unroll
    for (int o = 32; o > 0; o >>= 1) { s += __shfl_xor(s, o); s2 += __shfl_xor(s2, o); }
    float m = s * (1.f / 64.f);
    float var = s2 * (1.f / 64.f) - m * m;
    float rs = rsqrtf(var + 1e-5f);
    size_t off = ((size_t)b * LL + l0 + row) * CC + lane;
    xf[off] = v;
    Tb[row][lane] = f2b((v - m) * rs * gv + bv);
  }
  __syncthreads();
  // in-proj MFMA from LDS tile
  int wv = threadIdx.x >> 6;
  int lr = lane & 15, kg = lane >> 4;
  int m0 = wv * 16;
  int rowg0 = blockIdx.x * 64 + m0;       // == b*LL + l0 + m0
  bf16x8 a0 = *(const bf16x8*)&Tb[m0 + lr][kg * 8];
  bf16x8 a1 = *(const bf16x8*)&Tb[m0 + lr][32 + kg * 8];
  #pragma unroll
  for (int nt = 0; nt < 16; ++nt) {
    bf16x8 b0 = *(const bf16x8*)&w_b[(size_t)(nt * 16 + lr) * CC + kg * 8];
    bf16x8 b1 = *(const bf16x8*)&w_b[(size_t)(nt * 16 + lr) * CC + 32 + kg * 8];
    fx4 c = {0.f, 0.f, 0.f, 0.f};
    c = MFMA16(a0, b0, c, 0, 0, 0);
    c = MFMA16(a1, b1, c, 0, 0, 0);
    #pragma unroll
    for (int r = 0; r < 4; ++r) {
      int row = rowg0 + kg * 4 + r, col = nt * 16 + lr;
      unsigned short val = f2b(c[r]);
      if (col < 128) xin_b[(size_t)row * DI + col] = val;
      else           z_b[(size_t)row * DI + col - 128] = val;
    }
  }
}

// ---- fused scanA: x-proj MFMA (conv on the fly) + local scan; writes dbl, ap, hl ----
__global__ __launch_bounds__(128) void k_scanAX(const unsigned short* __restrict__ xin_b,
                                                const float* __restrict__ cw,
                                                const float* __restrict__ cb,
                                                const unsigned short* __restrict__ xpw_b,
                                                const float* __restrict__ Alog,
                                                const float* __restrict__ dtw,
                                                const float* __restrict__ dtbp,
                                                float* __restrict__ dbl,
                                                float* __restrict__ ap,
                                                float* __restrict__ hl) {
  int g = blockIdx.x % GCH;
  int b = blockIdx.x / GCH;
  __shared__ float dblS[32][40];
  {
    // phase X: per-wave 16-row x-proj tile
    int wv = threadIdx.x >> 6, lane = threadIdx.x & 63;
    int lr = lane & 15, kg = lane >> 4;
    int lloc = g * 32 + wv * 16 + lr;          // in-batch l of this A-frag row
    size_t row = (size_t)b * LL + lloc;
    const bf16x8 zv8 = {0, 0, 0, 0, 0, 0, 0, 0};
    fx4 acc[3];
    #pragma unroll
    for (int nt = 0; nt < 3; ++nt) acc[nt] = (fx4){0.f, 0.f, 0.f, 0.f};
    #pragma unroll
    for (int ks = 0; ks < 4; ++ks) {
      int cbase = ks * 32 + kg * 8;
      bf16x8 x3 = *(const bf16x8*)&xin_b[row * DI + cbase];
      bf16x8 x2 = (lloc >= 1) ? *(const bf16x8*)&xin_b[(row - 1) * DI + cbase] : zv8;
      bf16x8 x1 = (lloc >= 2) ? *(const bf16x8*)&xin_b[(row - 2) * DI + cbase] : zv8;
      bf16x8 x0 = (lloc >= 3) ? *(const bf16x8*)&xin_b[(row - 3) * DI + cbase] : zv8;
      bf16x8 a;
      #pragma unroll
      for (int e = 0; e < 8; ++e) {
        int d = cbase + e;
        float4 w4 = *(const float4*)&cw[d * 4];
        float v = cb[d] + b2f((unsigned short)x0[e]) * w4.x + b2f((unsigned short)x1[e]) * w4.y
                + b2f((unsigned short)x2[e]) * w4.z + b2f((unsigned short)x3[e]) * w4.w;
        a[e] = (short)f2b(silu_f(v));
      }
      #pragma unroll
      for (int nt = 0; nt < 3; ++nt) {
        bf16x8 bfr = *(const bf16x8*)&xpw_b[(size_t)(nt * 16 + lr) * DI + cbase];
        acc[nt] = MFMA16(a, bfr, acc[nt], 0, 0, 0);
      }
    }
    #pragma unroll
    for (int nt = 0; nt < 3; ++nt)
      #pragma unroll
      for (int r = 0; r < 4; ++r) {
        int col = nt * 16 + lr;
        if (col < 36) dblS[wv * 16 + kg * 4 + r][col] = acc[nt][r];
      }
  }
  __syncthreads();
  // coalesced dblS -> dbl (needed later by scanCO)
  {
    size_t base = ((size_t)b * LL + g * 32) * 36;
    #pragma unroll
    for (int i = 0; i < 9; ++i) {
      int e = i * 128 + threadIdx.x;   // < 1152
      dbl[base + e] = dblS[e / 36][e % 36];
    }
  }
  // phase S: local scan per d
  int d = threadIdx.x;
  float A[16];
  #pragma unroll
  for (int j = 0; j < 4; ++j) {
    float4 al = *(const float4*)&Alog[d * NS + j * 4];
    A[j * 4 + 0] = -__expf(al.x); A[j * 4 + 1] = -__expf(al.y);
    A[j * 4 + 2] = -__expf(al.z); A[j * 4 + 3] = -__expf(al.w);
  }
  float4 w4 = *(const float4*)&dtw[d * 4];
  float dtbv = dtbp[d];
  float4 cw4 = *(const float4*)&cw[d * 4];
  float cbv = cb[d];
  const unsigned short* xip = xin_b + ((size_t)b * LL + g * LCH) * DI + d;
  float w0 = 0.f, w1 = 0.f, w2 = 0.f;
  if (g > 0) {
    w0 = b2f(xip[-3 * DI]); w1 = b2f(xip[-2 * DI]); w2 = b2f(xip[-DI]);
  }
  float h[16];
  #pragma unroll
  for (int n = 0; n < 16; ++n) h[n] = 0.f;
  float dtsum = 0.f;
  #pragma unroll 4
  for (int l = 0; l < LCH; ++l) {
    float xv = b2f(xip[(size_t)l * DI]);
    float cacc = cbv + w0 * cw4.x + w1 * cw4.y + w2 * cw4.z + xv * cw4.w;
    float xcv = silu_f(cacc);
    w0 = w1; w1 = w2; w2 = xv;
    float4 q = *(float4*)&dblS[l][0];
    float v = dtbv + q.x * w4.x + q.y * w4.y + q.z * w4.z + q.w * w4.w;
    float dtv = softplus_f(v);
    float dx = dtv * xcv;
    dtsum += dtv;
    float4 b0 = *(float4*)&dblS[l][4];
    float4 b1 = *(float4*)&dblS[l][8];
    float4 b2 = *(float4*)&dblS[l][12];
    float4 b3 = *(float4*)&dblS[l][16];
    float a[16];
    #pragma unroll
    for (int n = 0; n < 16; ++n) a[n] = __expf(dtv * A[n]);
    h[0]  = a[0]  * h[0]  + dx * b0.x;  h[1]  = a[1]  * h[1]  + dx * b0.y;
    h[2]  = a[2]  * h[2]  + dx * b0.z;  h[3]  = a[3]  * h[3]  + dx * b0.w;
    h[4]  = a[4]  * h[4]  + dx * b1.x;  h[5]  = a[5]  * h[5]  + dx * b1.y;
    h[6]  = a[6]  * h[6]  + dx * b1.z;  h[7]  = a[7]  * h[7]  + dx * b1.w;
    h[8]  = a[8]  * h[8]  + dx * b2.x;  h[9]  = a[9]  * h[9]  + dx * b2.y;
    h[10] = a[10] * h[10] + dx * b2.z;  h[11] = a[11] * h[11] + dx * b2.w;
    h[12] = a[12] * h[12] + dx * b3.x;  h[13] = a[13] * h[13] + dx * b3.y;
    h[14] = a[14] * h[14] + dx * b3.z;  h[15] = a[15] * h[15] + dx * b3.w;
  }
  size_t o = (size_t)g * NSEQ + ((size_t)b * DI + d) * NS;
  #pragma unroll
  for (int j = 0; j < 4; ++j) {
    float4 av = make_float4(__expf(dtsum * A[j*4]), __expf(dtsum * A[j*4+1]),
                            __expf(dtsum * A[j*4+2]), __expf(dtsum * A[j*4+3]));
    *(float4*)&ap[o + j * 4] = av;
    *(float4*)&hl[o + j * 4] = make_float4(h[j*4], h[j*4+1], h[j*4+2], h[j*4+3]);
  }
}

// ---- fused scan2 (2a+2b+2c): full cross-chunk prefix, hi written in place of ap ----
__global__ __launch_bounds__(64) void k_scan2(const float* ap,   // == hi
                                              const float* __restrict__ hl,
                                              float* hi) {
  int s0 = blockIdx.x * 64;
  int t = threadIdx.x;
  __shared__ float apS[GS][68], hlS[GS][68];
  float h = 0.f;
  for (int grp = 0; grp < NG; ++grp) {
    int c0 = grp * GS;
    #pragma unroll
    for (int j = 0; j < 8; ++j) {
      int e = j * 64 + t;          // < 512 float4-slots
      int c = e >> 4, si = (e & 15) * 4;
      *(float4*)&apS[c][si] = *(const float4*)&ap[(size_t)(c0 + c) * NSEQ + s0 + si];
      *(float4*)&hlS[c][si] = *(const float4*)&hl[(size_t)(c0 + c) * NSEQ + s0 + si];
    }
    __syncthreads();
    #pragma unroll 4
    for (int c = 0; c < GS; ++c) {
      hi[(size_t)(c0 + c) * NSEQ + s0 + t] = h;   // overwrites ap region (tile already in LDS)
      h = apS[c][t] * h + hlS[c][t];
    }
    __syncthreads();
  }
}

// ---- fused scanC + out-proj + pr-proj: replay -> y in LDS -> GEMMs -> planar dst ----
__global__ __launch_bounds__(128) void k_scanCO(const float* __restrict__ dbl,
                                                const unsigned short* __restrict__ xin_b,
                                                const float* __restrict__ cw,
                                                const float* __restrict__ cb,
                                                const unsigned short* __restrict__ z_b,
                                                const float* __restrict__ Alog,
                                                const float* __restrict__ dtw,
                                                const float* __restrict__ dtbp,
                                                const float* __restrict__ Dp,
                                                const float* __restrict__ hi,
                                                const unsigned short* __restrict__ ow_b,
                                                const float* __restrict__ xf,
                                                const float* __restrict__ skipv,
                                                const unsigned short* __restrict__ pw_b,
                                                const float* __restrict__ pb,
                                                const float* __restrict__ ident,
                                                float* __restrict__ dst, int addid) {
  int g = blockIdx.x % GCH;
  int b = blockIdx.x / GCH;
  int d = threadIdx.x;
  __shared__ float Bms[LCH * NS];
  __shared__ float Cms[LCH * NS];
  __shared__ float Dts[LCH][4];
  __shared__ unsigned short yS[32][136];
  __shared__ unsigned short tmpS[32][72];
  float A[16];
  #pragma unroll
  for (int j = 0; j < 4; ++j) {
    float4 al = *(const float4*)&Alog[d * NS + j * 4];
    A[j * 4 + 0] = -__expf(al.x); A[j * 4 + 1] = -__expf(al.y);
    A[j * 4 + 2] = -__expf(al.z); A[j * 4 + 3] = -__expf(al.w);
  }
  float4 w4 = *(const float4*)&dtw[d * 4];
  float dtbv = dtbp[d];
  float Dv = Dp[d];
  float4 cw4 = *(const float4*)&cw[d * 4];
  float cbv = cb[d];
  {
    int idx = threadIdx.x * 4;
    int l = idx >> 4, n = idx & 15;
    size_t rb = ((size_t)b * LL + g * LCH + l) * 36;
    *(float4*)&Bms[idx] = *(const float4*)&dbl[rb + 4 + n];
    *(float4*)&Cms[idx] = *(const float4*)&dbl[rb + 20 + n];
    if (threadIdx.x < 32)
      *(float4*)&Dts[threadIdx.x][0] = *(const float4*)&dbl[((size_t)b * LL + g * LCH + threadIdx.x) * 36];
  }
  __syncthreads();
  size_t o = (size_t)g * NSEQ + ((size_t)b * DI + d) * NS;
  float h[16];
  #pragma unroll
  for (int j = 0; j < 4; ++j) {
    float4 hv = *(const float4*)&hi[o + j * 4];
    h[j * 4 + 0] = hv.x; h[j * 4 + 1] = hv.y; h[j * 4 + 2] = hv.z; h[j * 4 + 3] = hv.w;
  }
  size_t base = ((size_t)b * LL + g * LCH) * DI + d;
  const unsigned short* xip = xin_b + base;
  float w0 = 0.f, w1 = 0.f, w2 = 0.f;
  if (g > 0) {
    w0 = b2f(xip[-3 * DI]); w1 = b2f(xip[-2 * DI]); w2 = b2f(xip[-DI]);
  }
  #pragma unroll 4
  for (int l = 0; l < LCH; ++l) {
    float xv = b2f(xip[(size_t)l * DI]);
    float cacc = cbv + w0 * cw4.x + w1 * cw4.y + w2 * cw4.z + xv * cw4.w;
    float xcv = silu_f(cacc);
    w0 = w1; w1 = w2; w2 = xv;
    float zv = b2f(z_b[base + (size_t)l * DI]);
    float4 q = *(float4*)&Dts[l][0];
    float v = dtbv + q.x * w4.x + q.y * w4.y + q.z * w4.z + q.w * w4.w;
    float dtv = softplus_f(v);
    float4 b0 = *(float4*)&Bms[l * 16];
    float4 b1 = *(float4*)&Bms[l * 16 + 4];
    float4 b2 = *(float4*)&Bms[l * 16 + 8];
    float4 b3 = *(float4*)&Bms[l * 16 + 12];
    float4 c0 = *(float4*)&Cms[l * 16];
    float4 c1 = *(float4*)&Cms[l * 16 + 4];
    float4 c2 = *(float4*)&Cms[l * 16 + 8];
    float4 c3 = *(float4*)&Cms[l * 16 + 12];
    float a[16];
    #pragma unroll
    for (int n = 0; n < 16; ++n) a[n] = __expf(dtv * A[n]);
    float dx = dtv * xcv;
    float yv = Dv * xcv;
    h[0]  = a[0]  * h[0]  + dx * b0.x;  yv += h[0]  * c0.x;
    h[1]  = a[1]  * h[1]  + dx * b0.y;  yv += h[1]  * c0.y;
    h[2]  = a[2]  * h[2]  + dx * b0.z;  yv += h[2]  * c0.z;
    h[3]  = a[3]  * h[3]  + dx * b0.w;  yv += h[3]  * c0.w;
    h[4]  = a[4]  * h[4]  + dx * b1.x;  yv += h[4]  * c1.x;
    h[5]  = a[5]  * h[5]  + dx * b1.y;  yv += h[5]  * c1.y;
    h[6]  = a[6]  * h[6]  + dx * b1.z;  yv += h[6]  * c1.z;
    h[7]  = a[7]  * h[7]  + dx * b1.w;  yv += h[7]  * c1.w;
    h[8]  = a[8]  * h[8]  + dx * b2.x;  yv += h[8]  * c2.x;
    h[9]  = a[9]  * h[9]  + dx * b2.y;  yv += h[9]  * c2.y;
    h[10] = a[10] * h[10] + dx * b2.z;  yv += h[10] * c2.z;
    h[11] = a[11] * h[11] + dx * b2.w;  yv += h[11] * c2.w;
    h[12] = a[12] * h[12] + dx * b3.x;  yv += h[12] * c3.x;
    h[13] = a[13] * h[13] + dx * b3.y;  yv += h[13] * c3.y;
    h[14] = a[14] * h[14] + dx * b3.z;  yv += h[14] * c3.z;
    h[15] = a[15] * h[15] + dx * b3.w;  yv += h[15] * c3.w;
    float sg = silu_f(zv);
    yS[l][d] = f2b(yv * sg);
  }
  __syncthreads();
  // phase O: out-proj 16-row tile per wave + skip*xf -> tmpS
  int wv = threadIdx.x >> 6, lane = threadIdx.x & 63;
  int lr = lane & 15, kg = lane >> 4;
  {
    fx4 acc[4];
    #pragma unroll
    for (int nt = 0; nt < 4; ++nt) acc[nt] = (fx4){0.f, 0.f, 0.f, 0.f};
    #pragma unroll
    for (int ks = 0; ks < 4; ++ks) {
      bf16x8 a = *(const bf16x8*)&yS[wv * 16 + lr][ks * 32 + kg * 8];
      #pragma unroll
      for (int nt = 0; nt < 4; ++nt) {
        bf16x8 bfr = *(const bf16x8*)&ow_b[(size_t)(nt * 16 + lr) * DI + ks * 32 + kg * 8];
        acc[nt] = MFMA16(a, bfr, acc[nt], 0, 0, 0);
      }
    }
    float sk = skipv[0];
    #pragma unroll
    for (int nt = 0; nt < 4; ++nt) {
      #pragma unroll
      for (int r = 0; r < 4; ++r) {
        int rowl = wv * 16 + kg * 4 + r, col = nt * 16 + lr;
        size_t grow = (size_t)b * LL + g * 32 + rowl;
        float val = acc[nt][r] + sk * xf[grow * CC + col];
        tmpS[rowl][col] = f2b(val);
      }
    }
  }
  __syncthreads();
  // phase P: pr-proj, planar [c][l] store
  {
    fx4 pacc[4];
    #pragma unroll
    for (int ct = 0; ct < 4; ++ct) pacc[ct] = (fx4){0.f, 0.f, 0.f, 0.f};
    #pragma unroll
    for (int ks = 0; ks < 2; ++ks) {
      bf16x8 bfrag = *(const bf16x8*)&tmpS[wv * 16 + lr][ks * 32 + kg * 8];
      #pragma unroll
      for (int ct = 0; ct < 4; ++ct) {
        bf16x8 a = *(const bf16x8*)&pw_b[(size_t)(ct * 16 + lr) * CC + ks * 32 + kg * 8];
        pacc[ct] = MFMA16(a, bfrag, pacc[ct], 0, 0, 0);
      }
    }
    #pragma unroll
    for (int ct = 0; ct < 4; ++ct) {
      #pragma unroll
      for (int r = 0; r < 4; ++r) {
        int c = ct * 16 + kg * 4 + r;
        int lpos = g * 32 + wv * 16 + lr;
        size_t off = ((size_t)(b * CC + c)) * LL + lpos;
        float val = pacc[ct][r] + pb[c];
        if (addid) val += ident[off];
        dst[off] = val;
      }
    }
  }
}

extern "C" void kernel_launch(void* const* d_in, const int* in_sizes, int n_in,
                              void* d_out, int out_size, void* d_ws, size_t ws_size,
                              hipStream_t stream) {
  const float* x = (const float*)d_in[0];
  float* ws = (float*)d_ws;
  float* stats = ws;                                        //      1024 floats
  float* xf    = ws + 1024;                                 //  2359296 floats
  unsigned short* xin_b = (unsigned short*)(ws + 2360320);  //  4718592 shorts (2359296 f)
  unsigned short* z_b   = (unsigned short*)(ws + 4719616);  //  4718592 shorts (2359296 f)
  float* dbl   = ws + 7078912;                              //  1327104 floats
  float* ap    = ws + 8406016;                              //  2359296 (ap -> hi in place)
  float* hl    = ws + 10765312;                             //  2359296 (dead after scan2 -> inter)
  unsigned short* wb = (unsigned short*)(ws + 13124608);    //    69632 shorts
  float* inter = hl;   // hl dead after k_scan2; scanCO(L0) writes it; L1 reads it in
                       // stats/fusein BEFORE scanAX(L1) clobbers hl again.
  float* outp  = (float*)d_out;

  k_cvt<<<272, 256, 0, stream>>>((const float*)d_in[3], (const float*)d_in[6],
                                 (const float*)d_in[11], (const float*)d_in[13],
                                 (const float*)d_in[17], (const float*)d_in[20],
                                 (const float*)d_in[25], (const float*)d_in[27], wb);

  const float* cur = x;
  for (int layer = 0; layer < 2; ++layer) {
    const int p0 = 1 + 14 * layer;
    const float* ln_g   = (const float*)d_in[p0 + 0];
    const float* ln_b   = (const float*)d_in[p0 + 1];
    const float* conv_w = (const float*)d_in[p0 + 3];
    const float* conv_b = (const float*)d_in[p0 + 4];
    const float* dt_w   = (const float*)d_in[p0 + 6];
    const float* dt_b   = (const float*)d_in[p0 + 7];
    const float* A_log  = (const float*)d_in[p0 + 8];
    const float* Dp     = (const float*)d_in[p0 + 9];
    const float* skip   = (const float*)d_in[p0 + 11];
    const float* pr_b   = (const float*)d_in[p0 + 13];
    const unsigned short* inw_b = wb + (size_t)layer * 34816;
    const unsigned short* xpw_b = inw_b + 16384;
    const unsigned short* ow_b  = inw_b + 22528;
    const unsigned short* pw_b  = inw_b + 30720;
    float* dst = (layer == 0) ? inter : outp;

    k_stats <<<BB * CC, 256, 0, stream>>>(cur, stats);
    k_fusein<<<BB * NT, 256, 0, stream>>>(cur, stats, ln_g, ln_b, inw_b, xf, xin_b, z_b);
    k_scanAX<<<BB * GCH, 128, 0, stream>>>(xin_b, conv_w, conv_b, xpw_b, A_log,
                                           dt_w, dt_b, dbl, ap, hl);
    k_scan2 <<<NSEQ / 64, 64, 0, stream>>>(ap, hl, ap /*hi*/);
    k_scanCO<<<BB * GCH, 128, 0, stream>>>(dbl, xin_b, conv_w, conv_b, z_b, A_log,
                                           dt_w, dt_b, Dp, ap /*hi*/, ow_b, xf, skip,
                                           pw_b, pr_b, x, dst, layer);
    cur = inter;
  }
}

// Round 7
// 254.540 us; speedup vs baseline: 2.1773x; 1.1578x over previous
//
#include <hip/hip_runtime.h>
#include <math.h>

#define BB 4
#define CC 64
#define DI 128
#define NS 16
#define LL 9216
#define NT (LL / 64)

// scan decomposition
#define GCH 576
#define LCH 16
#define NSEQ 8192      // B*DI*NS
#define SD  512        // B*DI
#define NG 24
#define GS 24          // NG*GS == GCH

typedef __attribute__((ext_vector_type(8))) short bf16x8;
typedef __attribute__((ext_vector_type(4))) float fx4;
#define MFMA16 __builtin_amdgcn_mfma_f32_16x16x32_bf16

static __device__ __forceinline__ unsigned short f2b(float f) {
  unsigned u = __float_as_uint(f);
  u += 0x7fffu + ((u >> 16) & 1u);
  return (unsigned short)(u >> 16);
}
static __device__ __forceinline__ float b2f(unsigned short s) {
  return __uint_as_float(((unsigned)s) << 16);
}
static __device__ __forceinline__ float silu_f(float x) {
  return x / (1.f + __expf(-x));
}
static __device__ __forceinline__ float softplus_f(float v) {
  return fmaxf(v, 0.f) + __logf(1.f + __expf(-fabsf(v)));
}

// ---------------- weight bf16 conversion (once) ----------------
__global__ __launch_bounds__(256) void k_cvt(const float* __restrict__ inw1, const float* __restrict__ xpw1,
                                             const float* __restrict__ ow1, const float* __restrict__ pw1,
                                             const float* __restrict__ inw2, const float* __restrict__ xpw2,
                                             const float* __restrict__ ow2, const float* __restrict__ pw2,
                                             unsigned short* __restrict__ wb) {
  int idx = blockIdx.x * 256 + threadIdx.x;   // < 69632
  int layer = idx >= 34816;
  int e = idx - layer * 34816;
  const float* inw = layer ? inw2 : inw1;
  const float* xpw = layer ? xpw2 : xpw1;
  const float* ow = layer ? ow2 : ow1;
  const float* pw = layer ? pw2 : pw1;
  float v;
  if (e < 16384) v = inw[e];
  else if (e < 22528) { int t = e - 16384; int r = t >> 7, c = t & 127; v = (r < 36) ? xpw[r * 128 + c] : 0.f; }
  else if (e < 30720) v = ow[e - 22528];
  else v = pw[e - 30720];
  wb[idx] = f2b(v);
}

// ---------------- instance-norm moments per (b,c) ----------------
__global__ __launch_bounds__(256) void k_stats(const float* __restrict__ p,
                                               float* __restrict__ stats) {
  int bc = blockIdx.x;
  const float* row = p + (size_t)bc * LL;
  float s = 0.f, s2 = 0.f;
  for (int i = threadIdx.x; i < LL; i += 256) {
    float v = row[i];
    s += v; s2 += v * v;
  }
  #pragma unroll
  for (int o = 32; o > 0; o >>= 1) {
    s += __shfl_down(s, o);
    s2 += __shfl_down(s2, o);
  }
  __shared__ float red[8];
  int w = threadIdx.x >> 6;
  if ((threadIdx.x & 63) == 0) { red[w] = s; red[4 + w] = s2; }
  __syncthreads();
  if (threadIdx.x == 0) {
    float S = red[0] + red[1] + red[2] + red[3];
    float S2 = red[4] + red[5] + red[6] + red[7];
    float m = S * (1.f / LL);
    float var = S2 * (1.f / LL) - m * m;
    stats[bc * 2] = m;
    stats[bc * 2 + 1] = rsqrtf(var + 1e-5f);
  }
}

// ---- fused: transpose + IN + relu + LN + in-proj MFMA -> xf, xin_b, z_b ----
__global__ __launch_bounds__(256) void k_fusein(const float* __restrict__ p,
                                                const float* __restrict__ stats,
                                                const float* __restrict__ g,
                                                const float* __restrict__ be,
                                                const unsigned short* __restrict__ w_b,
                                                float* __restrict__ xf,
                                                unsigned short* __restrict__ xin_b,
                                                unsigned short* __restrict__ z_b) {
  int b = blockIdx.x / NT;
  int l0 = (blockIdx.x % NT) * 64;
  __shared__ float T[64][65];
  __shared__ unsigned short Tb[64][72];
  int li = threadIdx.x & 63;
  int c0 = threadIdx.x >> 6;
  #pragma unroll
  for (int j = 0; j < 16; ++j) {
    int c = c0 * 16 + j;
    float m = stats[(b * CC + c) * 2];
    float rs = stats[(b * CC + c) * 2 + 1];
    float v = p[((size_t)(b * CC + c)) * LL + l0 + li];
    T[li][c] = fmaxf((v - m) * rs, 0.f);
  }
  __syncthreads();
  int lane = threadIdx.x & 63;
  int w = threadIdx.x >> 6;
  float gv = g[lane], bv = be[lane];
  for (int j = 0; j < 16; ++j) {
    int row = w * 16 + j;
    float v = T[row][lane];
    float s = v, s2 = v * v;
    #pragma unroll
    for (int o = 32; o > 0; o >>= 1) { s += __shfl_xor(s, o); s2 += __shfl_xor(s2, o); }
    float m = s * (1.f / 64.f);
    float var = s2 * (1.f / 64.f) - m * m;
    float rs = rsqrtf(var + 1e-5f);
    size_t off = ((size_t)b * LL + l0 + row) * CC + lane;
    xf[off] = v;
    Tb[row][lane] = f2b((v - m) * rs * gv + bv);
  }
  __syncthreads();
  int wv = threadIdx.x >> 6;
  int lr = lane & 15, kg = lane >> 4;
  int m0 = wv * 16;
  int rowg0 = blockIdx.x * 64 + m0;
  bf16x8 a0 = *(const bf16x8*)&Tb[m0 + lr][kg * 8];
  bf16x8 a1 = *(const bf16x8*)&Tb[m0 + lr][32 + kg * 8];
  #pragma unroll
  for (int nt = 0; nt < 16; ++nt) {
    bf16x8 b0 = *(const bf16x8*)&w_b[(size_t)(nt * 16 + lr) * CC + kg * 8];
    bf16x8 b1 = *(const bf16x8*)&w_b[(size_t)(nt * 16 + lr) * CC + 32 + kg * 8];
    fx4 c = {0.f, 0.f, 0.f, 0.f};
    c = MFMA16(a0, b0, c, 0, 0, 0);
    c = MFMA16(a1, b1, c, 0, 0, 0);
    #pragma unroll
    for (int r = 0; r < 4; ++r) {
      int row = rowg0 + kg * 4 + r, col = nt * 16 + lr;
      unsigned short val = f2b(c[r]);
      if (col < 128) xin_b[(size_t)row * DI + col] = val;
      else           z_b[(size_t)row * DI + col - 128] = val;
    }
  }
}

// ---- fused scanA: split-K x-proj MFMA (conv on the fly) + local scan ----
// writes dbl, dtsum (dts), hl
__global__ __launch_bounds__(128) void k_scanAX(const unsigned short* __restrict__ xin_b,
                                                const float* __restrict__ cw,
                                                const float* __restrict__ cb,
                                                const unsigned short* __restrict__ xpw_b,
                                                const float* __restrict__ Alog,
                                                const float* __restrict__ dtw,
                                                const float* __restrict__ dtbp,
                                                float* __restrict__ dbl,
                                                float* __restrict__ dts,
                                                float* __restrict__ hl) {
  int g = blockIdx.x % GCH;
  int b = blockIdx.x / GCH;
  __shared__ float dblP[2][16][40];
  int wv = threadIdx.x >> 6, lane = threadIdx.x & 63;
  int lr = lane & 15, kg = lane >> 4;
  {
    int lloc = g * LCH + lr;
    size_t row = (size_t)b * LL + lloc;
    const bf16x8 zv8 = {0, 0, 0, 0, 0, 0, 0, 0};
    fx4 acc[3];
    #pragma unroll
    for (int nt = 0; nt < 3; ++nt) acc[nt] = (fx4){0.f, 0.f, 0.f, 0.f};
    #pragma unroll
    for (int kk = 0; kk < 2; ++kk) {
      int cbase = (wv * 2 + kk) * 32 + kg * 8;
      bf16x8 x3 = *(const bf16x8*)&xin_b[row * DI + cbase];
      bf16x8 x2 = (lloc >= 1) ? *(const bf16x8*)&xin_b[(row - 1) * DI + cbase] : zv8;
      bf16x8 x1 = (lloc >= 2) ? *(const bf16x8*)&xin_b[(row - 2) * DI + cbase] : zv8;
      bf16x8 x0 = (lloc >= 3) ? *(const bf16x8*)&xin_b[(row - 3) * DI + cbase] : zv8;
      bf16x8 a;
      #pragma unroll
      for (int e = 0; e < 8; ++e) {
        int d = cbase + e;
        float4 w4 = *(const float4*)&cw[d * 4];
        float v = cb[d] + b2f((unsigned short)x0[e]) * w4.x + b2f((unsigned short)x1[e]) * w4.y
                + b2f((unsigned short)x2[e]) * w4.z + b2f((unsigned short)x3[e]) * w4.w;
        a[e] = (short)f2b(silu_f(v));
      }
      #pragma unroll
      for (int nt = 0; nt < 3; ++nt) {
        bf16x8 bfr = *(const bf16x8*)&xpw_b[(size_t)(nt * 16 + lr) * DI + cbase];
        acc[nt] = MFMA16(a, bfr, acc[nt], 0, 0, 0);
      }
    }
    #pragma unroll
    for (int nt = 0; nt < 3; ++nt)
      #pragma unroll
      for (int r = 0; r < 4; ++r) {
        int col = nt * 16 + lr;
        if (col < 36) dblP[wv][kg * 4 + r][col] = acc[nt][r];
      }
  }
  __syncthreads();
  // sum split-K partials (into dblP[0]) + coalesced global write
  size_t dbase = ((size_t)b * LL + g * LCH) * 36;
  for (int e = threadIdx.x; e < 576; e += 128) {
    int r = e / 36, c = e - r * 36;
    float v = dblP[0][r][c] + dblP[1][r][c];
    dblP[0][r][c] = v;
    dbl[dbase + e] = v;
  }
  __syncthreads();
  // local scan per d
  int d = threadIdx.x;
  float A0 = -__expf(Alog[d * NS]);
  bool afast = true;
  #pragma unroll
  for (int n = 1; n < 16; ++n) {
    float An = -__expf(Alog[d * NS + n]);
    afast = afast && (fabsf(An - A0 * (float)(n + 1)) <= 1e-3f * (float)(n + 1) * fabsf(A0));
  }
  float4 w4 = *(const float4*)&dtw[d * 4];
  float dtbv = dtbp[d];
  float4 cw4 = *(const float4*)&cw[d * 4];
  float cbv = cb[d];
  const unsigned short* xip = xin_b + ((size_t)b * LL + g * LCH) * DI + d;
  float w0 = 0.f, w1 = 0.f, w2 = 0.f;
  if (g > 0) {
    w0 = b2f(xip[-3 * DI]); w1 = b2f(xip[-2 * DI]); w2 = b2f(xip[-DI]);
  }
  float h[16];
  #pragma unroll
  for (int n = 0; n < 16; ++n) h[n] = 0.f;
  float dtsum = 0.f;
  #pragma unroll 4
  for (int l = 0; l < LCH; ++l) {
    float xv = b2f(xip[(size_t)l * DI]);
    float cacc = cbv + w0 * cw4.x + w1 * cw4.y + w2 * cw4.z + xv * cw4.w;
    float xcv = silu_f(cacc);
    w0 = w1; w1 = w2; w2 = xv;
    float4 q = *(float4*)&dblP[0][l][0];
    float v = dtbv + q.x * w4.x + q.y * w4.y + q.z * w4.z + q.w * w4.w;
    float dtv = softplus_f(v);
    float dx = dtv * xcv;
    dtsum += dtv;
    float4 b0 = *(float4*)&dblP[0][l][4];
    float4 b1 = *(float4*)&dblP[0][l][8];
    float4 b2 = *(float4*)&dblP[0][l][12];
    float4 b3 = *(float4*)&dblP[0][l][16];
    float a[16];
    if (afast) {
      float e1 = __expf(dtv * A0);
      float p2 = e1 * e1, p4 = p2 * p2, p8 = p4 * p4;
      a[0] = e1;      a[1] = p2;      a[2] = p2 * e1;      a[3] = p4;
      a[4] = p4 * e1; a[5] = p4 * p2; a[6] = p4 * p2 * e1; a[7] = p8;
      a[8] = p8 * e1; a[9] = p8 * p2; a[10] = p8 * p2 * e1; a[11] = p8 * p4;
      a[12] = p8 * p4 * e1; a[13] = p8 * p4 * p2; a[14] = p8 * p4 * p2 * e1; a[15] = p8 * p8;
    } else {
      #pragma unroll
      for (int n = 0; n < 16; ++n) a[n] = __expf(dtv * -__expf(Alog[d * NS + n]));
    }
    h[0]  = a[0]  * h[0]  + dx * b0.x;  h[1]  = a[1]  * h[1]  + dx * b0.y;
    h[2]  = a[2]  * h[2]  + dx * b0.z;  h[3]  = a[3]  * h[3]  + dx * b0.w;
    h[4]  = a[4]  * h[4]  + dx * b1.x;  h[5]  = a[5]  * h[5]  + dx * b1.y;
    h[6]  = a[6]  * h[6]  + dx * b1.z;  h[7]  = a[7]  * h[7]  + dx * b1.w;
    h[8]  = a[8]  * h[8]  + dx * b2.x;  h[9]  = a[9]  * h[9]  + dx * b2.y;
    h[10] = a[10] * h[10] + dx * b2.z;  h[11] = a[11] * h[11] + dx * b2.w;
    h[12] = a[12] * h[12] + dx * b3.x;  h[13] = a[13] * h[13] + dx * b3.y;
    h[14] = a[14] * h[14] + dx * b3.z;  h[15] = a[15] * h[15] + dx * b3.w;
  }
  dts[(size_t)g * SD + b * DI + d] = dtsum;
  size_t o = (size_t)g * NSEQ + ((size_t)b * DI + d) * NS;
  #pragma unroll
  for (int j = 0; j < 4; ++j)
    *(float4*)&hl[o + j * 4] = make_float4(h[j * 4], h[j * 4 + 1], h[j * 4 + 2], h[j * 4 + 3]);
}

// ---- scan2a: per-group aggregates (a recomputed from dtsum — exact) ----
__global__ __launch_bounds__(256) void k_scan2a(const float* __restrict__ dts,
                                                const float* __restrict__ hl,
                                                const float* __restrict__ Alog,
                                                float* __restrict__ gap,
                                                float* __restrict__ ghl) {
  int t = blockIdx.x * 256 + threadIdx.x;   // < NG*NSEQ
  int grp = t >> 13, seq = t & (NSEQ - 1);
  int sd = seq >> 4;
  float An = -__expf(Alog[seq & (DI * NS - 1)]);
  float A = 1.f, H = 0.f;
  int c0 = grp * GS;
  #pragma unroll 4
  for (int c = 0; c < GS; ++c) {
    float a = __expf(An * dts[(size_t)(c0 + c) * SD + sd]);
    H = a * H + hl[(size_t)(c0 + c) * NSEQ + seq];
    A *= a;
  }
  gap[t] = A;
  ghl[t] = H;
}

// ---- scan2bc: redundant group-prefix + chunk carries ----
__global__ __launch_bounds__(256) void k_scan2bc(const float* __restrict__ dts,
                                                 const float* __restrict__ hl,
                                                 const float* __restrict__ gap,
                                                 const float* __restrict__ ghl,
                                                 const float* __restrict__ Alog,
                                                 float* __restrict__ hi) {
  int t = blockIdx.x * 256 + threadIdx.x;   // < NG*NSEQ
  int grp = t >> 13, seq = t & (NSEQ - 1);
  int sd = seq >> 4;
  float An = -__expf(Alog[seq & (DI * NS - 1)]);
  float h = 0.f;
  for (int gg = 0; gg < grp; ++gg)
    h = gap[gg * NSEQ + seq] * h + ghl[gg * NSEQ + seq];
  int c0 = grp * GS;
  #pragma unroll 4
  for (int c = 0; c < GS; ++c) {
    float a = __expf(An * dts[(size_t)(c0 + c) * SD + sd]);
    hi[(size_t)(c0 + c) * NSEQ + seq] = h;
    h = a * h + hl[(size_t)(c0 + c) * NSEQ + seq];
  }
}

// ---- fused scanC + out-proj + pr-proj (both split-K over 2 waves) ----
__global__ __launch_bounds__(128) void k_scanCO(const float* __restrict__ dbl,
                                                const unsigned short* __restrict__ xin_b,
                                                const float* __restrict__ cw,
                                                const float* __restrict__ cb,
                                                const unsigned short* __restrict__ z_b,
                                                const float* __restrict__ Alog,
                                                const float* __restrict__ dtw,
                                                const float* __restrict__ dtbp,
                                                const float* __restrict__ Dp,
                                                const float* __restrict__ hi,
                                                const unsigned short* __restrict__ ow_b,
                                                const float* __restrict__ xf,
                                                const float* __restrict__ skipv,
                                                const unsigned short* __restrict__ pw_b,
                                                const float* __restrict__ pb,
                                                const float* __restrict__ ident,
                                                float* __restrict__ dst, int addid) {
  int g = blockIdx.x % GCH;
  int b = blockIdx.x / GCH;
  int d = threadIdx.x;
  __shared__ float Bms[LCH * NS];
  __shared__ float Cms[LCH * NS];
  __shared__ float Dts[LCH][4];
  __shared__ unsigned short yS[16][136];
  __shared__ float Pf[2][1088];
  __shared__ unsigned short tmpS[16][72];
  {
    int tid = threadIdx.x;
    size_t rb0 = ((size_t)b * LL + g * LCH) * 36;
    if (tid < 64) {
      int l = tid >> 2, n4 = (tid & 3) * 4;
      *(float4*)&Bms[l * 16 + n4] = *(const float4*)&dbl[rb0 + (size_t)l * 36 + 4 + n4];
    } else {
      int l = (tid - 64) >> 2, n4 = (tid & 3) * 4;
      *(float4*)&Cms[l * 16 + n4] = *(const float4*)&dbl[rb0 + (size_t)l * 36 + 20 + n4];
    }
    if (tid < 16)
      *(float4*)&Dts[tid][0] = *(const float4*)&dbl[rb0 + (size_t)tid * 36];
  }
  float A0 = -__expf(Alog[d * NS]);
  bool afast = true;
  #pragma unroll
  for (int n = 1; n < 16; ++n) {
    float An = -__expf(Alog[d * NS + n]);
    afast = afast && (fabsf(An - A0 * (float)(n + 1)) <= 1e-3f * (float)(n + 1) * fabsf(A0));
  }
  float4 w4 = *(const float4*)&dtw[d * 4];
  float dtbv = dtbp[d];
  float Dv = Dp[d];
  float4 cw4 = *(const float4*)&cw[d * 4];
  float cbv = cb[d];
  __syncthreads();
  size_t o = (size_t)g * NSEQ + ((size_t)b * DI + d) * NS;
  float h[16];
  #pragma unroll
  for (int j = 0; j < 4; ++j) {
    float4 hv = *(const float4*)&hi[o + j * 4];
    h[j * 4 + 0] = hv.x; h[j * 4 + 1] = hv.y; h[j * 4 + 2] = hv.z; h[j * 4 + 3] = hv.w;
  }
  size_t base = ((size_t)b * LL + g * LCH) * DI + d;
  const unsigned short* xip = xin_b + base;
  float w0 = 0.f, w1 = 0.f, w2 = 0.f;
  if (g > 0) {
    w0 = b2f(xip[-3 * DI]); w1 = b2f(xip[-2 * DI]); w2 = b2f(xip[-DI]);
  }
  #pragma unroll 4
  for (int l = 0; l < LCH; ++l) {
    float xv = b2f(xip[(size_t)l * DI]);
    float cacc = cbv + w0 * cw4.x + w1 * cw4.y + w2 * cw4.z + xv * cw4.w;
    float xcv = silu_f(cacc);
    w0 = w1; w1 = w2; w2 = xv;
    float zv = b2f(z_b[base + (size_t)l * DI]);
    float4 q = *(float4*)&Dts[l][0];
    float v = dtbv + q.x * w4.x + q.y * w4.y + q.z * w4.z + q.w * w4.w;
    float dtv = softplus_f(v);
    float4 b0 = *(float4*)&Bms[l * 16];
    float4 b1 = *(float4*)&Bms[l * 16 + 4];
    float4 b2 = *(float4*)&Bms[l * 16 + 8];
    float4 b3 = *(float4*)&Bms[l * 16 + 12];
    float4 c0 = *(float4*)&Cms[l * 16];
    float4 c1 = *(float4*)&Cms[l * 16 + 4];
    float4 c2 = *(float4*)&Cms[l * 16 + 8];
    float4 c3 = *(float4*)&Cms[l * 16 + 12];
    float a[16];
    if (afast) {
      float e1 = __expf(dtv * A0);
      float p2 = e1 * e1, p4 = p2 * p2, p8 = p4 * p4;
      a[0] = e1;      a[1] = p2;      a[2] = p2 * e1;      a[3] = p4;
      a[4] = p4 * e1; a[5] = p4 * p2; a[6] = p4 * p2 * e1; a[7] = p8;
      a[8] = p8 * e1; a[9] = p8 * p2; a[10] = p8 * p2 * e1; a[11] = p8 * p4;
      a[12] = p8 * p4 * e1; a[13] = p8 * p4 * p2; a[14] = p8 * p4 * p2 * e1; a[15] = p8 * p8;
    } else {
      #pragma unroll
      for (int n = 0; n < 16; ++n) a[n] = __expf(dtv * -__expf(Alog[d * NS + n]));
    }
    float dx = dtv * xcv;
    float yv = Dv * xcv;
    h[0]  = a[0]  * h[0]  + dx * b0.x;  yv += h[0]  * c0.x;
    h[1]  = a[1]  * h[1]  + dx * b0.y;  yv += h[1]  * c0.y;
    h[2]  = a[2]  * h[2]  + dx * b0.z;  yv += h[2]  * c0.z;
    h[3]  = a[3]  * h[3]  + dx * b0.w;  yv += h[3]  * c0.w;
    h[4]  = a[4]  * h[4]  + dx * b1.x;  yv += h[4]  * c1.x;
    h[5]  = a[5]  * h[5]  + dx * b1.y;  yv += h[5]  * c1.y;
    h[6]  = a[6]  * h[6]  + dx * b1.z;  yv += h[6]  * c1.z;
    h[7]  = a[7]  * h[7]  + dx * b1.w;  yv += h[7]  * c1.w;
    h[8]  = a[8]  * h[8]  + dx * b2.x;  yv += h[8]  * c2.x;
    h[9]  = a[9]  * h[9]  + dx * b2.y;  yv += h[9]  * c2.y;
    h[10] = a[10] * h[10] + dx * b2.z;  yv += h[10] * c2.z;
    h[11] = a[11] * h[11] + dx * b2.w;  yv += h[11] * c2.w;
    h[12] = a[12] * h[12] + dx * b3.x;  yv += h[12] * c3.x;
    h[13] = a[13] * h[13] + dx * b3.y;  yv += h[13] * c3.y;
    h[14] = a[14] * h[14] + dx * b3.z;  yv += h[14] * c3.z;
    h[15] = a[15] * h[15] + dx * b3.w;  yv += h[15] * c3.w;
    float sg = silu_f(zv);
    yS[l][d] = f2b(yv * sg);
  }
  __syncthreads();
  // phase O: out-proj, split-K across the 2 waves
  int wv = threadIdx.x >> 6, lane = threadIdx.x & 63;
  int lr = lane & 15, kg = lane >> 4;
  {
    fx4 oacc[4];
    #pragma unroll
    for (int nt = 0; nt < 4; ++nt) oacc[nt] = (fx4){0.f, 0.f, 0.f, 0.f};
    #pragma unroll
    for (int kk = 0; kk < 2; ++kk) {
      int cbase = (wv * 2 + kk) * 32 + kg * 8;
      bf16x8 a = *(const bf16x8*)&yS[lr][cbase];
      #pragma unroll
      for (int nt = 0; nt < 4; ++nt) {
        bf16x8 bfr = *(const bf16x8*)&ow_b[(size_t)(nt * 16 + lr) * DI + cbase];
        oacc[nt] = MFMA16(a, bfr, oacc[nt], 0, 0, 0);
      }
    }
    #pragma unroll
    for (int nt = 0; nt < 4; ++nt)
      #pragma unroll
      for (int r = 0; r < 4; ++r)
        Pf[wv][(kg * 4 + r) * 68 + nt * 16 + lr] = oacc[nt][r];
  }
  __syncthreads();
  {
    int row = threadIdx.x >> 3, col0 = (threadIdx.x & 7) * 8;
    size_t grow = (size_t)b * LL + g * LCH + row;
    float4 xfa = *(const float4*)&xf[grow * CC + col0];
    float4 xfb = *(const float4*)&xf[grow * CC + col0 + 4];
    float sk = skipv[0];
    float xs[8] = {xfa.x, xfa.y, xfa.z, xfa.w, xfb.x, xfb.y, xfb.z, xfb.w};
    #pragma unroll
    for (int j = 0; j < 8; ++j) {
      int col = col0 + j;
      tmpS[row][col] = f2b(Pf[0][row * 68 + col] + Pf[1][row * 68 + col] + sk * xs[j]);
    }
  }
  __syncthreads();
  // phase P: pr-proj, split-K (ks = wave)
  {
    fx4 pacc[4];
    #pragma unroll
    for (int ct = 0; ct < 4; ++ct) pacc[ct] = (fx4){0.f, 0.f, 0.f, 0.f};
    int cbase = wv * 32 + kg * 8;
    bf16x8 bfrag = *(const bf16x8*)&tmpS[lr][cbase];
    #pragma unroll
    for (int ct = 0; ct < 4; ++ct) {
      bf16x8 a = *(const bf16x8*)&pw_b[(size_t)(ct * 16 + lr) * CC + cbase];
      pacc[ct] = MFMA16(a, bfrag, pacc[ct], 0, 0, 0);
    }
    #pragma unroll
    for (int ct = 0; ct < 4; ++ct)
      #pragma unroll
      for (int r = 0; r < 4; ++r)
        Pf[wv][(ct * 16 + kg * 4 + r) * 17 + lr] = pacc[ct][r];
  }
  __syncthreads();
  {
    int c = threadIdx.x >> 1, l0v = (threadIdx.x & 1) * 8;
    float pbv = pb[c];
    size_t obase = ((size_t)(b * CC + c)) * LL + g * LCH + l0v;
    #pragma unroll
    for (int j = 0; j < 8; ++j) {
      float v = Pf[0][c * 17 + l0v + j] + Pf[1][c * 17 + l0v + j] + pbv;
      if (addid) v += ident[obase + j];
      dst[obase + j] = v;
    }
  }
}

extern "C" void kernel_launch(void* const* d_in, const int* in_sizes, int n_in,
                              void* d_out, int out_size, void* d_ws, size_t ws_size,
                              hipStream_t stream) {
  const float* x = (const float*)d_in[0];
  float* ws = (float*)d_ws;
  float* stats = ws;                                        //      1024 floats
  float* xf    = ws + 1024;                                 //  2359296
  unsigned short* xin_b = (unsigned short*)(ws + 2360320);  //  4718592 shorts
  unsigned short* z_b   = (unsigned short*)(ws + 4719616);  //  4718592 shorts
  float* dbl   = ws + 7078912;                              //  1327104
  float* dts   = ws + 8406016;                              //   294912
  float* hl    = ws + 8700928;                              //  4718592 (dead after scan2bc -> inter)
  float* hi    = ws + 13419520;                             //  4718592
  float* gap   = ws + 18138112;                             //   196608
  float* ghl   = ws + 18334720;                             //   196608
  unsigned short* wb = (unsigned short*)(ws + 18531328);    //    69632 shorts
  float* inter = hl;   // hl dead after k_scan2bc; scanCO(L0) writes it; L1 reads it in
                       // stats/fusein BEFORE scanAX(L1) rewrites hl.
  float* outp  = (float*)d_out;

  k_cvt<<<272, 256, 0, stream>>>((const float*)d_in[3], (const float*)d_in[6],
                                 (const float*)d_in[11], (const float*)d_in[13],
                                 (const float*)d_in[17], (const float*)d_in[20],
                                 (const float*)d_in[25], (const float*)d_in[27], wb);

  const float* cur = x;
  for (int layer = 0; layer < 2; ++layer) {
    const int p0 = 1 + 14 * layer;
    const float* ln_g   = (const float*)d_in[p0 + 0];
    const float* ln_b   = (const float*)d_in[p0 + 1];
    const float* conv_w = (const float*)d_in[p0 + 3];
    const float* conv_b = (const float*)d_in[p0 + 4];
    const float* dt_w   = (const float*)d_in[p0 + 6];
    const float* dt_b   = (const float*)d_in[p0 + 7];
    const float* A_log  = (const float*)d_in[p0 + 8];
    const float* Dp     = (const float*)d_in[p0 + 9];
    const float* skip   = (const float*)d_in[p0 + 11];
    const float* pr_b   = (const float*)d_in[p0 + 13];
    const unsigned short* inw_b = wb + (size_t)layer * 34816;
    const unsigned short* xpw_b = inw_b + 16384;
    const unsigned short* ow_b  = inw_b + 22528;
    const unsigned short* pw_b  = inw_b + 30720;
    float* dst = (layer == 0) ? inter : outp;

    k_stats  <<<BB * CC, 256, 0, stream>>>(cur, stats);
    k_fusein <<<BB * NT, 256, 0, stream>>>(cur, stats, ln_g, ln_b, inw_b, xf, xin_b, z_b);
    k_scanAX <<<BB * GCH, 128, 0, stream>>>(xin_b, conv_w, conv_b, xpw_b, A_log,
                                            dt_w, dt_b, dbl, dts, hl);
    k_scan2a <<<(NG * NSEQ) / 256, 256, 0, stream>>>(dts, hl, A_log, gap, ghl);
    k_scan2bc<<<(NG * NSEQ) / 256, 256, 0, stream>>>(dts, hl, gap, ghl, A_log, hi);
    k_scanCO <<<BB * GCH, 128, 0, stream>>>(dbl, xin_b, conv_w, conv_b, z_b, A_log,
                                            dt_w, dt_b, Dp, hi, ow_b, xf, skip,
                                            pw_b, pr_b, x, dst, layer);
    cur = inter;
  }
}